// Round 12
// baseline (2219.256 us; speedup 1.0000x reference)
//
#include <hip/hip_runtime.h>
#include <math.h>
#include <stdint.h>

#define B 1024
#define H 512
#define E 256
#define L 128
#define LE (L*E)   // 32768

typedef _Float16 f16;
typedef _Float16 f16x8 __attribute__((ext_vector_type(8)));
typedef float f32x4 __attribute__((ext_vector_type(4)));
typedef const __attribute__((address_space(1))) uint32_t gu32;
typedef __attribute__((address_space(3))) uint32_t lu32;

// ---------------------------------------------------------------------------
// Persistent state in module device globals. Everything rewritten every call.
// ---------------------------------------------------------------------------
__device__ __align__(16) f16 g_Xs[128*16*4*4096];   // X images [t:128 pad][mt16][kt:4] 64x64
__device__ __align__(16) f16 g_Hh[128*16*8*4096];   // h(t) images, t=0..127 (134 MB)
__device__ __align__(16) f16 g_Ws[16*12*8192];      // gates W' [itile:16][kt:12] 128x64
__device__ __align__(16) f16 g_W1s[8*8192];         // W1' [kt:8] 128x64
__device__ __align__(16) f16 g_W2s[2*8192];         // W2' [kt:2] 128x64
__device__ __align__(16) f16 g_W3s[4*8192];         // W3' [nh:2][kt:2] 128x64
__device__ __align__(16) float g_bsum[2048];        // b_ih+b_hh, n=j*4+g order

// Flag-array barrier (round-11 winner): no atomic RMW. Arrival =
// release-store own flag; wait = lane-parallel relaxed polls + acquire.
struct __align__(128) Flag { unsigned int v; unsigned int pad[31]; };
__device__ Flag g_flags[8][32];

__device__ __forceinline__ float fsigm(float x) {
    return __builtin_amdgcn_rcpf(1.0f + __expf(-x));
}
__device__ __forceinline__ float ftanh(float x) {
    return 2.0f * __builtin_amdgcn_rcpf(1.0f + __expf(-2.0f * x)) - 1.0f;
}

// ---------------------------------------------------------------------------
// conv_w: gates W' fp16 tile images (gate-interleaved n=j*4+g) + bias sums
// ---------------------------------------------------------------------------
__global__ __launch_bounds__(256) void conv_w(
    const float* __restrict__ W_ih, const float* __restrict__ W_hh,
    const float* __restrict__ b_ih, const float* __restrict__ b_hh)
{
    int gid = blockIdx.x*256 + threadIdx.x;   // 196608
    int kb  = gid & 7;
    int r1  = gid >> 3;
    int row = r1 & 127;
    int r2  = r1 >> 7;
    int kt  = r2 % 12;
    int nt  = r2 / 12;
    int n = nt*128 + row;
    int g = n & 3, j = n >> 2;
    int wrow = g*512 + j;
    int k = kt*64 + kb*8;
    const float* src = (k < 256) ? (W_ih + wrow*256 + k)
                                 : (W_hh + wrow*512 + (k - 256));
    f16x8 v;
    #pragma unroll
    for (int e = 0; e < 8; ++e) v[e] = (f16)src[e];
    char* dst = (char*)g_Ws + (size_t)(nt*12 + kt)*16384
              + row*128 + ((kb*16) ^ ((row & 7) << 4));
    *(f16x8*)dst = v;
    if (gid < 2048) {
        int gg = gid & 3, jj = gid >> 2;
        g_bsum[gid] = b_ih[gg*512 + jj] + b_hh[gg*512 + jj];
    }
}

// ---------------------------------------------------------------------------
// conv_mlp: W1/W2/W3 fp16 tile images
// ---------------------------------------------------------------------------
__global__ __launch_bounds__(256) void conv_mlp(
    const float* __restrict__ W1, const float* __restrict__ W2,
    const float* __restrict__ W3)
{
    int gid = blockIdx.x*256 + threadIdx.x;   // 14336
    if (gid < 8192) {                         // W1 (128,512) -> 8 tiles
        int s = gid;
        int kb = s & 7, row = (s >> 3) & 127, kt = s >> 10;
        const float* src = W1 + row*512 + kt*64 + kb*8;
        f16x8 v;
        #pragma unroll
        for (int e = 0; e < 8; ++e) v[e] = (f16)src[e];
        char* dst = (char*)g_W1s + (size_t)kt*16384
                  + row*128 + ((kb*16) ^ ((row & 7) << 4));
        *(f16x8*)dst = v;
    } else if (gid < 10240) {                 // W2 (128,128) -> 2 tiles
        int s = gid - 8192;
        int kb = s & 7, row = (s >> 3) & 127, kt = s >> 10;
        const float* src = W2 + row*128 + kt*64 + kb*8;
        f16x8 v;
        #pragma unroll
        for (int e = 0; e < 8; ++e) v[e] = (f16)src[e];
        char* dst = (char*)g_W2s + (size_t)kt*16384
                  + row*128 + ((kb*16) ^ ((row & 7) << 4));
        *(f16x8*)dst = v;
    } else if (gid < 14336) {                 // W3 (256,128) -> [nh:2][kt:2]
        int s = gid - 10240;
        int kb = s & 7, r256 = (s >> 3) & 255, kt = s >> 11;
        int nh = r256 >> 7, row = r256 & 127;
        const float* src = W3 + r256*128 + kt*64 + kb*8;
        f16x8 v;
        #pragma unroll
        for (int e = 0; e < 8; ++e) v[e] = (f16)src[e];
        char* dst = (char*)g_W3s + (size_t)(nh*2 + kt)*16384
                  + row*128 + ((kb*16) ^ ((row & 7) << 4));
        *(f16x8*)dst = v;
    }
}

// ---------------------------------------------------------------------------
// conv_x: X fp16 tile images (coalesced: 32 consecutive lanes = 1 KB)
// ---------------------------------------------------------------------------
__global__ __launch_bounds__(256) void conv_x(const float* __restrict__ padded)
{
    int gid = blockIdx.x*256 + threadIdx.x;   // 127*1024*32 = 4161536 exact
    int kq = gid & 31;
    int b  = (gid >> 5) & 1023;
    int t  = gid >> 15;
    const float* src = padded + (size_t)b*LE + t*E + kq*8;
    float4 v0 = *(const float4*)src;
    float4 v1 = *(const float4*)(src + 4);
    f16x8 v;
    v[0]=(f16)v0.x; v[1]=(f16)v0.y; v[2]=(f16)v0.z; v[3]=(f16)v0.w;
    v[4]=(f16)v1.x; v[5]=(f16)v1.y; v[6]=(f16)v1.z; v[7]=(f16)v1.w;
    int kt = kq >> 3, kb = kq & 7;
    int row = b & 63, mt16 = b >> 6;
    char* dst = (char*)g_Xs + (size_t)((t*16 + mt16)*4 + kt)*8192
              + row*128 + ((kb*16) ^ ((row & 7) << 4));
    *(f16x8*)dst = v;
}

// ---------------------------------------------------------------------------
// init: g_Hh[0] <- hidden image, out row 0 <- one-hot, flags reset
// ---------------------------------------------------------------------------
__global__ __launch_bounds__(256) void init_kernel(
    const float* __restrict__ hidden, float* __restrict__ out)
{
    int i = blockIdx.x * 256 + threadIdx.x;
    if (i < 256) g_flags[i >> 5][i & 31].v = 0u;
    if (i < B*H) {
        float hv = hidden[i];
        int b = i >> 9, j = i & 511;
        int mt = b >> 6, row = b & 63, kt = j >> 6, kk = j & 63;
        char* dst = (char*)g_Hh + (size_t)(mt*8 + kt)*8192
                  + row*128 + ((kk*2) ^ ((row & 7) << 4));
        *(f16*)dst = (f16)hv;
    }
    if (i < B*E) {
        int b = i >> 8, e = i & 255;
        out[b*LE + e] = (e == 0) ? 1.0f : 0.0f;
    }
}

// ---------------------------------------------------------------------------
// step_all: persistent gates recurrence, FREE-RUNNING WAVES.
// 8 groups x 32 blocks, 256 threads. Block owns 128 rows x 64 gate-cols.
// B (96 KB) persistent read-only LDS -> ZERO s_barriers in the kt loop.
// A comes global->registers directly (per-lane addrs into the pre-swizzled
// images; 3-deep az[3][4] prefetch, static indices, compiler waits).
// Per-wave flag-wait inside kt1 (before issuing kt4's h prefetch).
// Per-wave epilogue: shfl transpose -> cell -> wave-private Hs slice ->
// coalesced nontemporal h store; ONE __syncthreads then flag release.
// ---------------------------------------------------------------------------
__global__ __launch_bounds__(256, 1) void step_all()
{
    __shared__ __align__(16) char lds[102400];        // 96 KB B + 4 KB Hs
    char* Bb = lds;
    f16 (*Hs)[16] = (f16 (*)[16])(lds + 98304);

    const int tid  = threadIdx.x;
    const int lane = tid & 63;
    const int wv   = tid >> 6;          // 0..3 (32-row strip)
    const int grp  = blockIdx.x & 7;    // row group (XCD-local heuristic)
    const int nt   = blockIdx.x >> 3;   // 0..31 col slice
    const int l15  = lane & 15;
    const int p    = l15 & 3;
    const int klo  = (lane >> 4) << 4;

    // ---- persistent B load (once) ----
    {
        const char* src = (const char*)g_Ws + (size_t)(nt >> 1)*12*16384
                        + (size_t)(nt & 1)*64*128;
        #pragma unroll
        for (int it = 0; it < 24; ++it) {
            int c = wv*24 + it;
            int kt = c >> 3, cc = c & 7;
            __builtin_amdgcn_global_load_lds(
                (gu32*)(src + (size_t)kt*16384 + cc*1024 + lane*16),
                (lu32*)(Bb + c*1024 + lane*16), 16, 0, 0);
        }
    }
    float4 bs4[4];
    #pragma unroll
    for (int n = 0; n < 4; ++n)
        bs4[n] = *(const float4*)&g_bsum[nt*64 + n*16 + (l15 >> 2)*4];

    float creg[2][4];
    #pragma unroll
    for (int m = 0; m < 2; ++m)
        #pragma unroll
        for (int n = 0; n < 4; ++n) creg[m][n] = 0.0f;

    // per-lane A addressing (frag m=0: rows wv*32+l15; m=1: +16)
    const int r0 = wv*32 + l15, r1 = r0 + 16;
    const int sub0 = r0 >> 6, row0 = r0 & 63;
    const int sub1 = r1 >> 6, row1 = r1 & 63;
    int offA[2][2];   // [frag][kkl] byte offset within a 64x64 image
    offA[0][0] = row0*128 + ((klo)    ^ ((row0 & 7) << 4));
    offA[0][1] = row0*128 + ((64+klo) ^ ((row0 & 7) << 4));
    offA[1][0] = row1*128 + ((klo)    ^ ((row1 & 7) << 4));
    offA[1][1] = row1*128 + ((64+klo) ^ ((row1 & 7) << 4));

    asm volatile("s_waitcnt vmcnt(0)" ::: "memory");
    __syncthreads();   // B resident before any B-read

    // A-frag loader: az entry = {f0k0, f0k1, f1k0, f1k1}
    f16x8 az[3][4];
    auto loada = [&](int t_, int kt_, int s_) {
        const char* i0;
        const char* i1;
        if (kt_ < 4) {
            i0 = (const char*)g_Xs + (size_t)((t_*16 + grp*2 + sub0)*4 + kt_)*8192;
            i1 = (const char*)g_Xs + (size_t)((t_*16 + grp*2 + sub1)*4 + kt_)*8192;
        } else {
            i0 = (const char*)g_Hh + (size_t)((t_*16 + grp*2 + sub0)*8 + (kt_-4))*8192;
            i1 = (const char*)g_Hh + (size_t)((t_*16 + grp*2 + sub1)*8 + (kt_-4))*8192;
        }
        az[s_][0] = *(const f16x8*)(i0 + offA[0][0]);
        az[s_][1] = *(const f16x8*)(i0 + offA[0][1]);
        az[s_][2] = *(const f16x8*)(i1 + offA[1][0]);
        az[s_][3] = *(const f16x8*)(i1 + offA[1][1]);
    };

    // per-wave group wait: lane-parallel relaxed polls, uniform acquire exit
    auto wave_wait = [&](unsigned int target) {
        for (;;) {
            unsigned int v = __hip_atomic_load(&g_flags[grp][lane & 31].v,
                               __ATOMIC_RELAXED, __HIP_MEMORY_SCOPE_AGENT);
            if (__all(v >= target)) break;
            __builtin_amdgcn_s_sleep(1);
        }
        (void)__hip_atomic_load(&g_flags[grp][0].v,
                __ATOMIC_ACQUIRE, __HIP_MEMORY_SCOPE_AGENT);
    };

    f32x4 acc[2][4];

    // prologue: X(0) kt0..kt2
    loada(0, 0, 0); loada(0, 1, 1); loada(0, 2, 2);

    #pragma unroll 1
    for (int t = 0; t < 127; ++t) {
        #pragma unroll
        for (int m = 0; m < 2; ++m)
            #pragma unroll
            for (int n = 0; n < 4; ++n) acc[m][n] = (f32x4){0.f,0.f,0.f,0.f};

        #pragma unroll
        for (int kt = 0; kt < 12; ++kt) {
            const int s = kt % 3;
            const char* Br = Bb + kt*8192;
            #pragma unroll
            for (int kkl = 0; kkl < 2; ++kkl) {
                const int kb = kkl*64 + klo;
                f16x8 b[4];
                #pragma unroll
                for (int n = 0; n < 4; ++n) {
                    int r = n*16 + l15;
                    b[n] = *(const f16x8*)(Br + r*128 + (kb ^ ((r & 7) << 4)));
                }
                #pragma unroll
                for (int n = 0; n < 4; ++n) {
                    acc[0][n] = __builtin_amdgcn_mfma_f32_16x16x32_f16(
                        az[s][0 + kkl], b[n], acc[0][n], 0, 0, 0);
                    acc[1][n] = __builtin_amdgcn_mfma_f32_16x16x32_f16(
                        az[s][2 + kkl], b[n], acc[1][n], 0, 0, 0);
                }
            }
            // prefetch kt+3 into the slot just consumed (SSA renames WAR)
            if (kt == 1) wave_wait((unsigned)t);      // h(t) visible before kt4 issue
            if (kt < 9)       loada(t, kt + 3, s);
            else              loada(t + 1, kt - 9, s);   // X(t+1) kt0..2 (padded)
        }

        // ---- per-wave epilogue: transpose -> cell -> Hs slice ----
        #pragma unroll
        for (int m = 0; m < 2; ++m)
            #pragma unroll
            for (int n = 0; n < 4; ++n) {
                float v0 = acc[m][n][0], v1 = acc[m][n][1];
                float v2 = acc[m][n][2], v3 = acc[m][n][3];
                float s, r;
                s = (p & 1) ? v0 : v1; r = __shfl_xor(s, 1); if (p & 1) v0 = r; else v1 = r;
                s = (p & 1) ? v2 : v3; r = __shfl_xor(s, 1); if (p & 1) v2 = r; else v3 = r;
                s = (p & 2) ? v0 : v2; r = __shfl_xor(s, 2); if (p & 2) v0 = r; else v2 = r;
                s = (p & 2) ? v1 : v3; r = __shfl_xor(s, 2); if (p & 2) v1 = r; else v3 = r;
                float iv = fsigm(v0 + bs4[n].x);
                float fv = fsigm(v1 + bs4[n].y);
                float gg = ftanh(v2 + bs4[n].z);
                float ov = fsigm(v3 + bs4[n].w);
                float cv = fv * creg[m][n] + iv * gg;
                creg[m][n] = cv;
                float hv = ov * ftanh(cv);
                int rowl = wv*32 + m*16 + ((lane >> 4) << 2) + p;
                int coll = n*4 + (l15 >> 2);
                Hs[rowl][coll] = (f16)hv;
            }
        asm volatile("s_waitcnt lgkmcnt(0)" ::: "memory");  // wave's Hs writes done
        {
            char* hout = (char*)g_Hh + (size_t)(t + 1)*16*8*8192;
            int rowl = wv*32 + (lane >> 1), half = lane & 1;
            int row = grp*128 + rowl;
            int jg  = nt*16 + half*8;
            f16x8 hv8 = *(const f16x8*)(&Hs[rowl][half*8]);
            char* hd = hout + (size_t)((row >> 6)*8 + (jg >> 6))*8192
                     + (row & 63)*128 + (((jg & 63)*2) ^ ((row & 7) << 4));
            __builtin_nontemporal_store(hv8, (f16x8*)hd);
        }
        asm volatile("s_waitcnt vmcnt(0)" ::: "memory");  // h stores drained
        __syncthreads();                                  // all waves done
        if (tid == 0)
            __hip_atomic_store(&g_flags[grp][nt].v, (unsigned)(t + 1),
                               __ATOMIC_RELEASE, __HIP_MEMORY_SCOPE_AGENT);
    }
}

// ---------------------------------------------------------------------------
// mlp_all: batched 3-layer MLP for ALL tokens (round-4 proven structure).
// Block bi: tok = 1 + bi/16 (reads g_Hh[tok]), rows [mt*64,+64), mt = bi&15.
// ---------------------------------------------------------------------------
__global__ __launch_bounds__(256) void mlp_all(
    const float* __restrict__ b1, const float* __restrict__ b2,
    const float* __restrict__ b3, float* __restrict__ out)
{
    __shared__ char lds[65536];
    char* Wb = lds;            // 2 x 16384
    char* Ab = lds + 32768;    // 2 x 8192 (later Z2)
    char* Z1 = lds + 49152;    // 16384
    const int tid  = threadIdx.x;
    const int lane = tid & 63;
    const int w    = tid >> 6;
    const int bi   = blockIdx.x;
    const int tok  = 1 + (bi >> 4);
    const int mt   = bi & 15;
    const char* gH = (const char*)g_Hh + (size_t)(tok*16 + mt)*8*8192;
    float* outb = out + (size_t)(mt*64)*LE + (size_t)tok*E;

    float b1v[2], b2v[2], b3v[2][2];
    #pragma unroll
    for (int n = 0; n < 2; ++n) {
        int col = w*32 + n*16 + (lane & 15);
        b1v[n] = b1[col]; b2v[n] = b2[col];
        b3v[0][n] = b3[col]; b3v[1][n] = b3[128 + col];
    }
    const int kb0_0 = ((lane >> 4) << 4);

    f32x4 acc[4][2];
    #pragma unroll
    for (int m = 0; m < 4; ++m) { acc[m][0] = (f32x4){0,0,0,0}; acc[m][1] = (f32x4){0,0,0,0}; }

    #pragma unroll
    for (int it = 0; it < 2; ++it) {
        int c = w*2 + it;
        __builtin_amdgcn_global_load_lds((gu32*)(gH + c*1024 + lane*16),
                                         (lu32*)(Ab + c*1024 + lane*16), 16, 0, 0);
    }
    #pragma unroll
    for (int it = 0; it < 4; ++it) {
        int c = w*4 + it;
        __builtin_amdgcn_global_load_lds((gu32*)((const char*)g_W1s + c*1024 + lane*16),
                                         (lu32*)(Wb + c*1024 + lane*16), 16, 0, 0);
    }
    __syncthreads();

    for (int kt = 0; kt < 8; ++kt) {
        const int cur = kt & 1;
        if (kt < 7) {
            const char* gA = gH + (size_t)(kt+1)*8192;
            const char* gW = (const char*)g_W1s + (size_t)(kt+1)*16384;
            char* dA = Ab + (cur^1)*8192;
            char* dW = Wb + (cur^1)*16384;
            #pragma unroll
            for (int it = 0; it < 2; ++it) {
                int c = w*2 + it;
                __builtin_amdgcn_global_load_lds((gu32*)(gA + c*1024 + lane*16),
                                                 (lu32*)(dA + c*1024 + lane*16), 16, 0, 0);
            }
            #pragma unroll
            for (int it = 0; it < 4; ++it) {
                int c = w*4 + it;
                __builtin_amdgcn_global_load_lds((gu32*)(gW + c*1024 + lane*16),
                                                 (lu32*)(dW + c*1024 + lane*16), 16, 0, 0);
            }
        }
        const char* Ar = Ab + cur*8192;
        const char* Br = Wb + cur*16384;
        #pragma unroll
        for (int kk = 0; kk < 2; ++kk) {
            const int kb0 = kk*64 + kb0_0;
            f16x8 a[4], b[2];
            #pragma unroll
            for (int m = 0; m < 4; ++m) {
                int ar = m*16 + (lane & 15);
                a[m] = *(const f16x8*)(Ar + ar*128 + (kb0 ^ ((ar & 7) << 4)));
            }
            #pragma unroll
            for (int n = 0; n < 2; ++n) {
                int br = w*32 + n*16 + (lane & 15);
                b[n] = *(const f16x8*)(Br + br*128 + (kb0 ^ ((br & 7) << 4)));
            }
            #pragma unroll
            for (int m = 0; m < 4; ++m)
                #pragma unroll
                for (int n = 0; n < 2; ++n)
                    acc[m][n] = __builtin_amdgcn_mfma_f32_16x16x32_f16(a[m], b[n], acc[m][n], 0, 0, 0);
        }
        __syncthreads();
    }

    #pragma unroll
    for (int m = 0; m < 4; ++m)
        #pragma unroll
        for (int n = 0; n < 2; ++n)
            #pragma unroll
            for (int i = 0; i < 4; ++i) {
                int row = m*16 + ((lane >> 4) << 2) + i;
                int col = w*32 + n*16 + (lane & 15);
                float v = fmaxf(acc[m][n][i] + b1v[n], 0.0f);
                *(f16*)(Z1 + (col >> 6)*8192 + row*128
                        + (((col & 63)*2) ^ ((row & 7) << 4))) = (f16)v;
            }
    __syncthreads();

    #pragma unroll
    for (int it = 0; it < 8; ++it) {
        int c = w*8 + it;
        __builtin_amdgcn_global_load_lds((gu32*)((const char*)g_W2s + c*1024 + lane*16),
                                         (lu32*)(Wb + c*1024 + lane*16), 16, 0, 0);
    }
    __syncthreads();
    #pragma unroll
    for (int m = 0; m < 4; ++m) { acc[m][0] = (f32x4){0,0,0,0}; acc[m][1] = (f32x4){0,0,0,0}; }
    #pragma unroll
    for (int kt = 0; kt < 2; ++kt)
        #pragma unroll
        for (int kk = 0; kk < 2; ++kk) {
            const int kb0 = kk*64 + kb0_0;
            f16x8 a[4], b[2];
            #pragma unroll
            for (int m = 0; m < 4; ++m) {
                int ar = m*16 + (lane & 15);
                a[m] = *(const f16x8*)(Z1 + kt*8192 + ar*128 + (kb0 ^ ((ar & 7) << 4)));
            }
            #pragma unroll
            for (int n = 0; n < 2; ++n) {
                int br = w*32 + n*16 + (lane & 15);
                b[n] = *(const f16x8*)(Wb + kt*16384 + br*128 + (kb0 ^ ((br & 7) << 4)));
            }
            #pragma unroll
            for (int m = 0; m < 4; ++m)
                #pragma unroll
                for (int n = 0; n < 2; ++n)
                    acc[m][n] = __builtin_amdgcn_mfma_f32_16x16x32_f16(a[m], b[n], acc[m][n], 0, 0, 0);
        }
    __syncthreads();

    #pragma unroll
    for (int m = 0; m < 4; ++m)
        #pragma unroll
        for (int n = 0; n < 2; ++n)
            #pragma unroll
            for (int i = 0; i < 4; ++i) {
                int row = m*16 + ((lane >> 4) << 2) + i;
                int col = w*32 + n*16 + (lane & 15);
                float v = fmaxf(acc[m][n][i] + b2v[n], 0.0f);
                *(f16*)(Ab + (col >> 6)*8192 + row*128
                        + (((col & 63)*2) ^ ((row & 7) << 4))) = (f16)v;
            }
    __syncthreads();

    #pragma unroll
    for (int nh = 0; nh < 2; ++nh) {
        #pragma unroll
        for (int it = 0; it < 8; ++it) {
            int c = w*8 + it;
            __builtin_amdgcn_global_load_lds(
                (gu32*)((const char*)g_W3s + (size_t)nh*32768 + c*1024 + lane*16),
                (lu32*)(Wb + c*1024 + lane*16), 16, 0, 0);
        }
        __syncthreads();
        #pragma unroll
        for (int m = 0; m < 4; ++m) { acc[m][0] = (f32x4){0,0,0,0}; acc[m][1] = (f32x4){0,0,0,0}; }
        #pragma unroll
        for (int kt = 0; kt < 2; ++kt)
            #pragma unroll
            for (int kk = 0; kk < 2; ++kk) {
                const int kb0 = kk*64 + kb0_0;
                f16x8 a[4], b[2];
                #pragma unroll
                for (int m = 0; m < 4; ++m) {
                    int ar = m*16 + (lane & 15);
                    a[m] = *(const f16x8*)(Ab + kt*8192 + ar*128 + (kb0 ^ ((ar & 7) << 4)));
                }
                #pragma unroll
                for (int n = 0; n < 2; ++n) {
                    int br = w*32 + n*16 + (lane & 15);
                    b[n] = *(const f16x8*)(Wb + kt*16384 + br*128 + (kb0 ^ ((br & 7) << 4)));
                }
                #pragma unroll
                for (int m = 0; m < 4; ++m)
                    #pragma unroll
                    for (int n = 0; n < 2; ++n)
                        acc[m][n] = __builtin_amdgcn_mfma_f32_16x16x32_f16(a[m], b[n], acc[m][n], 0, 0, 0);
            }
        #pragma unroll
        for (int m = 0; m < 4; ++m)
            #pragma unroll
            for (int n = 0; n < 2; ++n)
                #pragma unroll
                for (int i = 0; i < 4; ++i) {
                    int row = m*16 + ((lane >> 4) << 2) + i;
                    int col = nh*128 + w*32 + n*16 + (lane & 15);
                    outb[(size_t)row*LE + col] = acc[m][n][i] + b3v[nh][n];
                }
        __syncthreads();
    }
}

// ---------------------------------------------------------------------------
extern "C" void kernel_launch(void* const* d_in, const int* in_sizes, int n_in,
                              void* d_out, int out_size, void* d_ws, size_t ws_size,
                              hipStream_t stream) {
    (void)in_sizes; (void)n_in; (void)out_size; (void)d_ws; (void)ws_size;
    const float* hidden = (const float*)d_in[0];
    const float* padded = (const float*)d_in[1];
    const float* W_ih   = (const float*)d_in[2];
    const float* W_hh   = (const float*)d_in[3];
    const float* b_ih   = (const float*)d_in[4];
    const float* b_hh   = (const float*)d_in[5];
    const float* W1     = (const float*)d_in[6];
    const float* b1     = (const float*)d_in[7];
    const float* W2     = (const float*)d_in[8];
    const float* b2     = (const float*)d_in[9];
    const float* W3     = (const float*)d_in[10];
    const float* b3     = (const float*)d_in[11];
    float* out = (float*)d_out;

    conv_w<<<768, 256, 0, stream>>>(W_ih, W_hh, b_ih, b_hh);
    conv_mlp<<<56, 256, 0, stream>>>(W1, W2, W3);
    conv_x<<<16256, 256, 0, stream>>>(padded);
    init_kernel<<<2048, 256, 0, stream>>>(hidden, out);
    step_all<<<256, 256, 0, stream>>>();
    mlp_all<<<2032, 256, 0, stream>>>(b1, b2, b3, out);
}

// Round 13
// 2172.950 us; speedup vs baseline: 1.0213x; 1.0213x over previous
//
#include <hip/hip_runtime.h>
#include <math.h>
#include <stdint.h>

#define B 1024
#define H 512
#define E 256
#define L 128
#define LE (L*E)   // 32768

typedef _Float16 f16;
typedef _Float16 f16x8 __attribute__((ext_vector_type(8)));
typedef float f32x4 __attribute__((ext_vector_type(4)));
typedef const __attribute__((address_space(1))) uint32_t gu32;
typedef __attribute__((address_space(3))) uint32_t lu32;

// ---------------------------------------------------------------------------
// Persistent state in module device globals. Everything rewritten every call.
// ---------------------------------------------------------------------------
__device__ __align__(16) f16 g_Xs[128*16*4*4096];   // X images [t:128 pad][mt16][kt:4] 64x64
__device__ __align__(16) f16 g_Hh[128*16*8*4096];   // h(t) images, t=0..127 (134 MB)
__device__ __align__(16) f16 g_Ws[16*12*8192];      // gates W' [itile:16][kt:12] 128x64
__device__ __align__(16) f16 g_W1s[8*8192];         // W1' [kt:8] 128x64
__device__ __align__(16) f16 g_W2s[2*8192];         // W2' [kt:2] 128x64
__device__ __align__(16) f16 g_W3s[4*8192];         // W3' [nh:2][kt:2] 128x64
__device__ __align__(16) float g_bsum[2048];        // b_ih+b_hh, n=j*4+g order

// Flag-array barrier (round-11 winner): no atomic RMW. Arrival =
// release-store own flag; wait = lane-parallel relaxed polls + acquire.
struct __align__(128) Flag { unsigned int v; unsigned int pad[31]; };
__device__ Flag g_flags[8][32];

__device__ __forceinline__ float fsigm(float x) {
    return __builtin_amdgcn_rcpf(1.0f + __expf(-x));
}
__device__ __forceinline__ float ftanh(float x) {
    return 2.0f * __builtin_amdgcn_rcpf(1.0f + __expf(-2.0f * x)) - 1.0f;
}

// ---------------------------------------------------------------------------
// conv_w: gates W' fp16 tile images (gate-interleaved n=j*4+g) + bias sums
// ---------------------------------------------------------------------------
__global__ __launch_bounds__(256) void conv_w(
    const float* __restrict__ W_ih, const float* __restrict__ W_hh,
    const float* __restrict__ b_ih, const float* __restrict__ b_hh)
{
    int gid = blockIdx.x*256 + threadIdx.x;   // 196608
    int kb  = gid & 7;
    int r1  = gid >> 3;
    int row = r1 & 127;
    int r2  = r1 >> 7;
    int kt  = r2 % 12;
    int nt  = r2 / 12;
    int n = nt*128 + row;
    int g = n & 3, j = n >> 2;
    int wrow = g*512 + j;
    int k = kt*64 + kb*8;
    const float* src = (k < 256) ? (W_ih + wrow*256 + k)
                                 : (W_hh + wrow*512 + (k - 256));
    f16x8 v;
    #pragma unroll
    for (int e = 0; e < 8; ++e) v[e] = (f16)src[e];
    char* dst = (char*)g_Ws + (size_t)(nt*12 + kt)*16384
              + row*128 + ((kb*16) ^ ((row & 7) << 4));
    *(f16x8*)dst = v;
    if (gid < 2048) {
        int gg = gid & 3, jj = gid >> 2;
        g_bsum[gid] = b_ih[gg*512 + jj] + b_hh[gg*512 + jj];
    }
}

// ---------------------------------------------------------------------------
// conv_mlp: W1/W2/W3 fp16 tile images
// ---------------------------------------------------------------------------
__global__ __launch_bounds__(256) void conv_mlp(
    const float* __restrict__ W1, const float* __restrict__ W2,
    const float* __restrict__ W3)
{
    int gid = blockIdx.x*256 + threadIdx.x;   // 14336
    if (gid < 8192) {                         // W1 (128,512) -> 8 tiles
        int s = gid;
        int kb = s & 7, row = (s >> 3) & 127, kt = s >> 10;
        const float* src = W1 + row*512 + kt*64 + kb*8;
        f16x8 v;
        #pragma unroll
        for (int e = 0; e < 8; ++e) v[e] = (f16)src[e];
        char* dst = (char*)g_W1s + (size_t)kt*16384
                  + row*128 + ((kb*16) ^ ((row & 7) << 4));
        *(f16x8*)dst = v;
    } else if (gid < 10240) {                 // W2 (128,128) -> 2 tiles
        int s = gid - 8192;
        int kb = s & 7, row = (s >> 3) & 127, kt = s >> 10;
        const float* src = W2 + row*128 + kt*64 + kb*8;
        f16x8 v;
        #pragma unroll
        for (int e = 0; e < 8; ++e) v[e] = (f16)src[e];
        char* dst = (char*)g_W2s + (size_t)kt*16384
                  + row*128 + ((kb*16) ^ ((row & 7) << 4));
        *(f16x8*)dst = v;
    } else if (gid < 14336) {                 // W3 (256,128) -> [nh:2][kt:2]
        int s = gid - 10240;
        int kb = s & 7, r256 = (s >> 3) & 255, kt = s >> 11;
        int nh = r256 >> 7, row = r256 & 127;
        const float* src = W3 + r256*128 + kt*64 + kb*8;
        f16x8 v;
        #pragma unroll
        for (int e = 0; e < 8; ++e) v[e] = (f16)src[e];
        char* dst = (char*)g_W3s + (size_t)(nh*2 + kt)*16384
                  + row*128 + ((kb*16) ^ ((row & 7) << 4));
        *(f16x8*)dst = v;
    }
}

// ---------------------------------------------------------------------------
// conv_x: X fp16 tile images (coalesced: 32 consecutive lanes = 1 KB)
// ---------------------------------------------------------------------------
__global__ __launch_bounds__(256) void conv_x(const float* __restrict__ padded)
{
    int gid = blockIdx.x*256 + threadIdx.x;   // 127*1024*32 = 4161536 exact
    int kq = gid & 31;
    int b  = (gid >> 5) & 1023;
    int t  = gid >> 15;
    const float* src = padded + (size_t)b*LE + t*E + kq*8;
    float4 v0 = *(const float4*)src;
    float4 v1 = *(const float4*)(src + 4);
    f16x8 v;
    v[0]=(f16)v0.x; v[1]=(f16)v0.y; v[2]=(f16)v0.z; v[3]=(f16)v0.w;
    v[4]=(f16)v1.x; v[5]=(f16)v1.y; v[6]=(f16)v1.z; v[7]=(f16)v1.w;
    int kt = kq >> 3, kb = kq & 7;
    int row = b & 63, mt16 = b >> 6;
    char* dst = (char*)g_Xs + (size_t)((t*16 + mt16)*4 + kt)*8192
              + row*128 + ((kb*16) ^ ((row & 7) << 4));
    *(f16x8*)dst = v;
}

// ---------------------------------------------------------------------------
// init: g_Hh[0] <- hidden image, out row 0 <- one-hot, flags reset
// ---------------------------------------------------------------------------
__global__ __launch_bounds__(256) void init_kernel(
    const float* __restrict__ hidden, float* __restrict__ out)
{
    int i = blockIdx.x * 256 + threadIdx.x;
    if (i < 256) g_flags[i >> 5][i & 31].v = 0u;
    if (i < B*H) {
        float hv = hidden[i];
        int b = i >> 9, j = i & 511;
        int mt = b >> 6, row = b & 63, kt = j >> 6, kk = j & 63;
        char* dst = (char*)g_Hh + (size_t)(mt*8 + kt)*8192
                  + row*128 + ((kk*2) ^ ((row & 7) << 4));
        *(f16*)dst = (f16)hv;
    }
    if (i < B*E) {
        int b = i >> 8, e = i & 255;
        out[b*LE + e] = (e == 0) ? 1.0f : 0.0f;
    }
}

// ---------------------------------------------------------------------------
// step_all: persistent gates recurrence, WAVE-PRIVATE staging, zero s_barrier
// in the kt loop. 8 groups x 32 blocks, 256 threads. Block owns 128 rows x
// 64 gate-cols; wave wv owns rows [wv*32,+32). B (96 KB) persistent LDS.
// A: 4 wave-private 4 KB slots (coalesced global_load_lds), counted per-wave
// vmcnt (kt0->12, else 8). Wave-private flag-wait at kt1-end (>=2-kt lead
// before kt4's first H read). Epilogue per-wave: transpose -> cell -> Hs
// (aliases own slot2) -> coalesced REGULAR store. One __syncthreads/step.
// ---------------------------------------------------------------------------
__global__ __launch_bounds__(256, 1) void step_all()
{
    __shared__ __align__(16) char lds[163840];   // 96K B + 4 waves x 16K slots
    char* Bb = lds;

    const int tid  = threadIdx.x;
    const int lane = tid & 63;
    const int wv   = tid >> 6;          // 0..3 (32-row strip)
    const int grp  = blockIdx.x & 7;    // row group
    const int nt   = blockIdx.x >> 3;   // 0..31 col slice
    const int l15  = lane & 15;
    const int p    = l15 & 3;
    const int klo  = (lane >> 4) << 4;

    char* Aw = lds + 98304 + wv*16384;            // wave-private 4 slots x 4 KB
    f16*  HsW = (f16*)(Aw + 2*4096);              // aliases own slot2 (1 KB used)
    const int sub    = wv >> 1;                   // which 64-row image
    const int rowoff = (wv & 1)*32;               // row offset within image

    // ---- persistent B load (once) ----
    {
        const char* src = (const char*)g_Ws + (size_t)(nt >> 1)*12*16384
                        + (size_t)(nt & 1)*64*128;
        #pragma unroll
        for (int it = 0; it < 24; ++it) {
            int c = wv*24 + it;
            int kt = c >> 3, cc = c & 7;
            __builtin_amdgcn_global_load_lds(
                (gu32*)(src + (size_t)kt*16384 + cc*1024 + lane*16),
                (lu32*)(Bb + c*1024 + lane*16), 16, 0, 0);
        }
    }
    float4 bs4[4];
    #pragma unroll
    for (int n = 0; n < 4; ++n)
        bs4[n] = *(const float4*)&g_bsum[nt*64 + n*16 + (l15 >> 2)*4];

    float creg[2][4];
    #pragma unroll
    for (int m = 0; m < 2; ++m)
        #pragma unroll
        for (int n = 0; n < 4; ++n) creg[m][n] = 0.0f;

    // wave-private A stage: 4 KB (this wave's 32 rows of one 64x64 image)
    auto stageA = [&](int t_, int kt_, int slot) {
        char* dst = Aw + slot*4096;
        const char* base = (kt_ < 4)
            ? (const char*)g_Xs + (size_t)((t_*16 + grp*2 + sub)*4 + kt_)*8192
            : (const char*)g_Hh + (size_t)((t_*16 + grp*2 + sub)*8 + (kt_-4))*8192;
        const char* src = base + rowoff*128;
        #pragma unroll
        for (int it = 0; it < 4; ++it)
            __builtin_amdgcn_global_load_lds(
                (gu32*)(src + it*1024 + lane*16),
                (lu32*)(dst + it*1024 + lane*16), 16, 0, 0);
    };

    // per-wave group wait: lane-parallel relaxed polls, acquire on exit
    auto wave_wait = [&](unsigned int target) {
        for (;;) {
            unsigned int v = __hip_atomic_load(&g_flags[grp][lane & 31].v,
                               __ATOMIC_RELAXED, __HIP_MEMORY_SCOPE_AGENT);
            if (__all(v >= target)) break;
            __builtin_amdgcn_s_sleep(1);
        }
        (void)__hip_atomic_load(&g_flags[grp][0].v,
                __ATOMIC_ACQUIRE, __HIP_MEMORY_SCOPE_AGENT);
    };

    // prologue: X(0) kt0..kt3 -> slots 0..3
    stageA(0, 0, 0); stageA(0, 1, 1); stageA(0, 2, 2); stageA(0, 3, 3);
    asm volatile("s_waitcnt vmcnt(0)" ::: "memory");
    __syncthreads();   // B + first A resident

    f32x4 acc[2][4];

    #pragma unroll 1
    for (int t = 0; t < 127; ++t) {
        if (t > 0) { stageA(t, 2, 2); stageA(t, 3, 3); }
        #pragma unroll
        for (int m = 0; m < 2; ++m)
            #pragma unroll
            for (int n = 0; n < 4; ++n) acc[m][n] = (f32x4){0.f,0.f,0.f,0.f};

        #pragma unroll
        for (int kt = 0; kt < 12; ++kt) {
            // per-wave counted wait for THIS kt's own 4 loads (no s_barrier)
            if (kt == 0) asm volatile("s_waitcnt vmcnt(12)" ::: "memory");
            else         asm volatile("s_waitcnt vmcnt(8)"  ::: "memory");
            const char* Ar = Aw + (kt & 3)*4096;
            const char* Br = Bb + kt*8192;
            #pragma unroll
            for (int kkl = 0; kkl < 2; ++kkl) {
                const int kb = kkl*64 + klo;
                f16x8 a[2], b[4];
                #pragma unroll
                for (int m = 0; m < 2; ++m) {
                    int rl = m*16 + l15;               // local row in wave slice
                    a[m] = *(const f16x8*)(Ar + rl*128 + (kb ^ ((rl & 7) << 4)));
                }
                #pragma unroll
                for (int n = 0; n < 4; ++n) {
                    int r = n*16 + l15;
                    b[n] = *(const f16x8*)(Br + r*128 + (kb ^ ((r & 7) << 4)));
                }
                #pragma unroll
                for (int m = 0; m < 2; ++m)
                    #pragma unroll
                    for (int n = 0; n < 4; ++n)
                        acc[m][n] = __builtin_amdgcn_mfma_f32_16x16x32_f16(
                            a[m], b[n], acc[m][n], 0, 0, 0);
            }
            // end-of-kt wave-private restage: slot (kt+3)&3 last read at kt-1
            if (kt == 1) { wave_wait((unsigned)t); stageA(t, 4, 0); }
            if (kt >= 2 && kt <= 8) stageA(t, kt + 3, (kt + 3) & 3);
            if (kt == 9)  stageA(t + 1, 0, 0);      // X(t+1); g_Xs padded
            if (kt == 10) stageA(t + 1, 1, 1);
        }

        // ---- per-wave epilogue: transpose -> cell -> HsW (own slot2) ----
        #pragma unroll
        for (int m = 0; m < 2; ++m)
            #pragma unroll
            for (int n = 0; n < 4; ++n) {
                float v0 = acc[m][n][0], v1 = acc[m][n][1];
                float v2 = acc[m][n][2], v3 = acc[m][n][3];
                float s, r;
                s = (p & 1) ? v0 : v1; r = __shfl_xor(s, 1); if (p & 1) v0 = r; else v1 = r;
                s = (p & 1) ? v2 : v3; r = __shfl_xor(s, 1); if (p & 1) v2 = r; else v3 = r;
                s = (p & 2) ? v0 : v2; r = __shfl_xor(s, 2); if (p & 2) v0 = r; else v2 = r;
                s = (p & 2) ? v1 : v3; r = __shfl_xor(s, 2); if (p & 2) v1 = r; else v3 = r;
                float iv = fsigm(v0 + bs4[n].x);
                float fv = fsigm(v1 + bs4[n].y);
                float gg = ftanh(v2 + bs4[n].z);
                float ov = fsigm(v3 + bs4[n].w);
                float cv = fv * creg[m][n] + iv * gg;
                creg[m][n] = cv;
                float hv = ov * ftanh(cv);
                int rl   = m*16 + ((lane >> 4) << 2) + p;   // 0..31 local row
                int coll = n*4 + (l15 >> 2);                // 0..15
                HsW[rl*16 + coll] = (f16)hv;
            }
        asm volatile("s_waitcnt lgkmcnt(0)" ::: "memory");  // wave's Hs done
        {
            char* hout = (char*)g_Hh + (size_t)(t + 1)*16*8*8192;
            int rl = lane >> 1, half = lane & 1;
            int row = grp*128 + wv*32 + rl;
            int jg  = nt*16 + half*8;
            f16x8 hv8 = *(const f16x8*)(&HsW[rl*16 + half*8]);
            char* hd = hout + (size_t)((row >> 6)*8 + (jg >> 6))*8192
                     + (row & 63)*128 + (((jg & 63)*2) ^ ((row & 7) << 4));
            *(f16x8*)hd = hv8;
        }
        asm volatile("s_waitcnt vmcnt(0)" ::: "memory");  // drain h (+X') loads
        __syncthreads();                                  // all waves done
        if (tid == 0)
            __hip_atomic_store(&g_flags[grp][nt].v, (unsigned)(t + 1),
                               __ATOMIC_RELEASE, __HIP_MEMORY_SCOPE_AGENT);
    }
}

// ---------------------------------------------------------------------------
// mlp_all: batched 3-layer MLP for ALL tokens (round-4 proven structure).
// Block bi: tok = 1 + bi/16 (reads g_Hh[tok]), rows [mt*64,+64), mt = bi&15.
// ---------------------------------------------------------------------------
__global__ __launch_bounds__(256) void mlp_all(
    const float* __restrict__ b1, const float* __restrict__ b2,
    const float* __restrict__ b3, float* __restrict__ out)
{
    __shared__ char lds[65536];
    char* Wb = lds;            // 2 x 16384
    char* Ab = lds + 32768;    // 2 x 8192 (later Z2)
    char* Z1 = lds + 49152;    // 16384
    const int tid  = threadIdx.x;
    const int lane = tid & 63;
    const int w    = tid >> 6;
    const int bi   = blockIdx.x;
    const int tok  = 1 + (bi >> 4);
    const int mt   = bi & 15;
    const char* gH = (const char*)g_Hh + (size_t)(tok*16 + mt)*8*8192;
    float* outb = out + (size_t)(mt*64)*LE + (size_t)tok*E;

    float b1v[2], b2v[2], b3v[2][2];
    #pragma unroll
    for (int n = 0; n < 2; ++n) {
        int col = w*32 + n*16 + (lane & 15);
        b1v[n] = b1[col]; b2v[n] = b2[col];
        b3v[0][n] = b3[col]; b3v[1][n] = b3[128 + col];
    }
    const int kb0_0 = ((lane >> 4) << 4);

    f32x4 acc[4][2];
    #pragma unroll
    for (int m = 0; m < 4; ++m) { acc[m][0] = (f32x4){0,0,0,0}; acc[m][1] = (f32x4){0,0,0,0}; }

    #pragma unroll
    for (int it = 0; it < 2; ++it) {
        int c = w*2 + it;
        __builtin_amdgcn_global_load_lds((gu32*)(gH + c*1024 + lane*16),
                                         (lu32*)(Ab + c*1024 + lane*16), 16, 0, 0);
    }
    #pragma unroll
    for (int it = 0; it < 4; ++it) {
        int c = w*4 + it;
        __builtin_amdgcn_global_load_lds((gu32*)((const char*)g_W1s + c*1024 + lane*16),
                                         (lu32*)(Wb + c*1024 + lane*16), 16, 0, 0);
    }
    __syncthreads();

    for (int kt = 0; kt < 8; ++kt) {
        const int cur = kt & 1;
        if (kt < 7) {
            const char* gA = gH + (size_t)(kt+1)*8192;
            const char* gW = (const char*)g_W1s + (size_t)(kt+1)*16384;
            char* dA = Ab + (cur^1)*8192;
            char* dW = Wb + (cur^1)*16384;
            #pragma unroll
            for (int it = 0; it < 2; ++it) {
                int c = w*2 + it;
                __builtin_amdgcn_global_load_lds((gu32*)(gA + c*1024 + lane*16),
                                                 (lu32*)(dA + c*1024 + lane*16), 16, 0, 0);
            }
            #pragma unroll
            for (int it = 0; it < 4; ++it) {
                int c = w*4 + it;
                __builtin_amdgcn_global_load_lds((gu32*)(gW + c*1024 + lane*16),
                                                 (lu32*)(dW + c*1024 + lane*16), 16, 0, 0);
            }
        }
        const char* Ar = Ab + cur*8192;
        const char* Br = Wb + cur*16384;
        #pragma unroll
        for (int kk = 0; kk < 2; ++kk) {
            const int kb0 = kk*64 + kb0_0;
            f16x8 a[4], b[2];
            #pragma unroll
            for (int m = 0; m < 4; ++m) {
                int ar = m*16 + (lane & 15);
                a[m] = *(const f16x8*)(Ar + ar*128 + (kb0 ^ ((ar & 7) << 4)));
            }
            #pragma unroll
            for (int n = 0; n < 2; ++n) {
                int br = w*32 + n*16 + (lane & 15);
                b[n] = *(const f16x8*)(Br + br*128 + (kb0 ^ ((br & 7) << 4)));
            }
            #pragma unroll
            for (int m = 0; m < 4; ++m)
                #pragma unroll
                for (int n = 0; n < 2; ++n)
                    acc[m][n] = __builtin_amdgcn_mfma_f32_16x16x32_f16(a[m], b[n], acc[m][n], 0, 0, 0);
        }
        __syncthreads();
    }

    #pragma unroll
    for (int m = 0; m < 4; ++m)
        #pragma unroll
        for (int n = 0; n < 2; ++n)
            #pragma unroll
            for (int i = 0; i < 4; ++i) {
                int row = m*16 + ((lane >> 4) << 2) + i;
                int col = w*32 + n*16 + (lane & 15);
                float v = fmaxf(acc[m][n][i] + b1v[n], 0.0f);
                *(f16*)(Z1 + (col >> 6)*8192 + row*128
                        + (((col & 63)*2) ^ ((row & 7) << 4))) = (f16)v;
            }
    __syncthreads();

    #pragma unroll
    for (int it = 0; it < 8; ++it) {
        int c = w*8 + it;
        __builtin_amdgcn_global_load_lds((gu32*)((const char*)g_W2s + c*1024 + lane*16),
                                         (lu32*)(Wb + c*1024 + lane*16), 16, 0, 0);
    }
    __syncthreads();
    #pragma unroll
    for (int m = 0; m < 4; ++m) { acc[m][0] = (f32x4){0,0,0,0}; acc[m][1] = (f32x4){0,0,0,0}; }
    #pragma unroll
    for (int kt = 0; kt < 2; ++kt)
        #pragma unroll
        for (int kk = 0; kk < 2; ++kk) {
            const int kb0 = kk*64 + kb0_0;
            f16x8 a[4], b[2];
            #pragma unroll
            for (int m = 0; m < 4; ++m) {
                int ar = m*16 + (lane & 15);
                a[m] = *(const f16x8*)(Z1 + kt*8192 + ar*128 + (kb0 ^ ((ar & 7) << 4)));
            }
            #pragma unroll
            for (int n = 0; n < 2; ++n) {
                int br = w*32 + n*16 + (lane & 15);
                b[n] = *(const f16x8*)(Wb + kt*16384 + br*128 + (kb0 ^ ((br & 7) << 4)));
            }
            #pragma unroll
            for (int m = 0; m < 4; ++m)
                #pragma unroll
                for (int n = 0; n < 2; ++n)
                    acc[m][n] = __builtin_amdgcn_mfma_f32_16x16x32_f16(a[m], b[n], acc[m][n], 0, 0, 0);
        }
    __syncthreads();

    #pragma unroll
    for (int m = 0; m < 4; ++m)
        #pragma unroll
        for (int n = 0; n < 2; ++n)
            #pragma unroll
            for (int i = 0; i < 4; ++i) {
                int row = m*16 + ((lane >> 4) << 2) + i;
                int col = w*32 + n*16 + (lane & 15);
                float v = fmaxf(acc[m][n][i] + b2v[n], 0.0f);
                *(f16*)(Ab + (col >> 6)*8192 + row*128
                        + (((col & 63)*2) ^ ((row & 7) << 4))) = (f16)v;
            }
    __syncthreads();

    #pragma unroll
    for (int nh = 0; nh < 2; ++nh) {
        #pragma unroll
        for (int it = 0; it < 8; ++it) {
            int c = w*8 + it;
            __builtin_amdgcn_global_load_lds(
                (gu32*)((const char*)g_W3s + (size_t)nh*32768 + c*1024 + lane*16),
                (lu32*)(Wb + c*1024 + lane*16), 16, 0, 0);
        }
        __syncthreads();
        #pragma unroll
        for (int m = 0; m < 4; ++m) { acc[m][0] = (f32x4){0,0,0,0}; acc[m][1] = (f32x4){0,0,0,0}; }
        #pragma unroll
        for (int kt = 0; kt < 2; ++kt)
            #pragma unroll
            for (int kk = 0; kk < 2; ++kk) {
                const int kb0 = kk*64 + kb0_0;
                f16x8 a[4], b[2];
                #pragma unroll
                for (int m = 0; m < 4; ++m) {
                    int ar = m*16 + (lane & 15);
                    a[m] = *(const f16x8*)(Ab + kt*8192 + ar*128 + (kb0 ^ ((ar & 7) << 4)));
                }
                #pragma unroll
                for (int n = 0; n < 2; ++n) {
                    int br = w*32 + n*16 + (lane & 15);
                    b[n] = *(const f16x8*)(Wb + kt*16384 + br*128 + (kb0 ^ ((br & 7) << 4)));
                }
                #pragma unroll
                for (int m = 0; m < 4; ++m)
                    #pragma unroll
                    for (int n = 0; n < 2; ++n)
                        acc[m][n] = __builtin_amdgcn_mfma_f32_16x16x32_f16(a[m], b[n], acc[m][n], 0, 0, 0);
            }
        #pragma unroll
        for (int m = 0; m < 4; ++m)
            #pragma unroll
            for (int n = 0; n < 2; ++n)
                #pragma unroll
                for (int i = 0; i < 4; ++i) {
                    int row = m*16 + ((lane >> 4) << 2) + i;
                    int col = nh*128 + w*32 + n*16 + (lane & 15);
                    outb[(size_t)row*LE + col] = acc[m][n][i] + b3v[nh][n];
                }
        __syncthreads();
    }
}

// ---------------------------------------------------------------------------
extern "C" void kernel_launch(void* const* d_in, const int* in_sizes, int n_in,
                              void* d_out, int out_size, void* d_ws, size_t ws_size,
                              hipStream_t stream) {
    (void)in_sizes; (void)n_in; (void)out_size; (void)d_ws; (void)ws_size;
    const float* hidden = (const float*)d_in[0];
    const float* padded = (const float*)d_in[1];
    const float* W_ih   = (const float*)d_in[2];
    const float* W_hh   = (const float*)d_in[3];
    const float* b_ih   = (const float*)d_in[4];
    const float* b_hh   = (const float*)d_in[5];
    const float* W1     = (const float*)d_in[6];
    const float* b1     = (const float*)d_in[7];
    const float* W2     = (const float*)d_in[8];
    const float* b2     = (const float*)d_in[9];
    const float* W3     = (const float*)d_in[10];
    const float* b3     = (const float*)d_in[11];
    float* out = (float*)d_out;

    conv_w<<<768, 256, 0, stream>>>(W_ih, W_hh, b_ih, b_hh);
    conv_mlp<<<56, 256, 0, stream>>>(W1, W2, W3);
    conv_x<<<16256, 256, 0, stream>>>(padded);
    init_kernel<<<2048, 256, 0, stream>>>(hidden, out);
    step_all<<<256, 256, 0, stream>>>();
    mlp_all<<<2032, 256, 0, stream>>>(b1, b2, b3, out);
}

// Round 15
// 873.503 us; speedup vs baseline: 2.5406x; 2.4876x over previous
//
#include <hip/hip_runtime.h>
#include <math.h>
#include <stdint.h>

#define B 1024
#define H 512
#define E 256
#define L 128
#define LE (L*E)   // 32768

typedef _Float16 f16;
typedef _Float16 f16x8 __attribute__((ext_vector_type(8)));
typedef float f32x4 __attribute__((ext_vector_type(4)));
typedef const __attribute__((address_space(1))) uint32_t gu32;
typedef __attribute__((address_space(3))) uint32_t lu32;

// ---------------------------------------------------------------------------
// Persistent state in module device globals. Everything rewritten every call.
// ---------------------------------------------------------------------------
__device__ __align__(16) f16 g_Xs[128*16*4*4096];   // X images [t:128 pad][mt16][kt:4] 64x64
__device__ __align__(16) f16 g_Hh[128*16*8*4096];   // h(t) images, t=0..127 (134 MB)
__device__ __align__(16) f16 g_Ws[16*12*8192];      // gates W' [itile:16][kt:12] 128x64
__device__ __align__(16) f16 g_W1s[8*8192];         // W1' [kt:8] 128x64
__device__ __align__(16) f16 g_W2s[2*8192];         // W2' [kt:2] 128x64
__device__ __align__(16) f16 g_W3s[4*8192];         // W3' [nh:2][kt:2] 128x64
__device__ __align__(16) float g_bsum[2048];        // b_ih+b_hh, n=j*4+g order

// Flag array (one line per flag) + per-XCD slot counters. Groups are
// PHYSICAL XCDs (grp = HW_REG_XCC_ID), so the h-exchange lives entirely in
// one shared L2: no release-wbl2, no acquire-buffer_inv needed. h addresses
// are t-indexed (first touch every step) -> no stale-L1 hazard. Flags use
// RELAXED agent atomics (LLC-homed 4B, cheap vs full L2 flush/inv).
struct __align__(128) Flag { unsigned int v; unsigned int pad[31]; };
__device__ Flag g_flags[8][32];
__device__ unsigned int g_slot[8];

__device__ __forceinline__ float fsigm(float x) {
    return __builtin_amdgcn_rcpf(1.0f + __expf(-x));
}
__device__ __forceinline__ float ftanh(float x) {
    return 2.0f * __builtin_amdgcn_rcpf(1.0f + __expf(-2.0f * x)) - 1.0f;
}

// ---------------------------------------------------------------------------
// conv_w: gates W' fp16 tile images (gate-interleaved n=j*4+g) + bias sums
// ---------------------------------------------------------------------------
__global__ __launch_bounds__(256) void conv_w(
    const float* __restrict__ W_ih, const float* __restrict__ W_hh,
    const float* __restrict__ b_ih, const float* __restrict__ b_hh)
{
    int gid = blockIdx.x*256 + threadIdx.x;   // 196608
    int kb  = gid & 7;
    int r1  = gid >> 3;
    int row = r1 & 127;
    int r2  = r1 >> 7;
    int kt  = r2 % 12;
    int nt  = r2 / 12;
    int n = nt*128 + row;
    int g = n & 3, j = n >> 2;
    int wrow = g*512 + j;
    int k = kt*64 + kb*8;
    const float* src = (k < 256) ? (W_ih + wrow*256 + k)
                                 : (W_hh + wrow*512 + (k - 256));
    f16x8 v;
    #pragma unroll
    for (int e = 0; e < 8; ++e) v[e] = (f16)src[e];
    char* dst = (char*)g_Ws + (size_t)(nt*12 + kt)*16384
              + row*128 + ((kb*16) ^ ((row & 7) << 4));
    *(f16x8*)dst = v;
    if (gid < 2048) {
        int gg = gid & 3, jj = gid >> 2;
        g_bsum[gid] = b_ih[gg*512 + jj] + b_hh[gg*512 + jj];
    }
}

// ---------------------------------------------------------------------------
// conv_mlp: W1/W2/W3 fp16 tile images
// ---------------------------------------------------------------------------
__global__ __launch_bounds__(256) void conv_mlp(
    const float* __restrict__ W1, const float* __restrict__ W2,
    const float* __restrict__ W3)
{
    int gid = blockIdx.x*256 + threadIdx.x;   // 14336
    if (gid < 8192) {                         // W1 (128,512) -> 8 tiles
        int s = gid;
        int kb = s & 7, row = (s >> 3) & 127, kt = s >> 10;
        const float* src = W1 + row*512 + kt*64 + kb*8;
        f16x8 v;
        #pragma unroll
        for (int e = 0; e < 8; ++e) v[e] = (f16)src[e];
        char* dst = (char*)g_W1s + (size_t)kt*16384
                  + row*128 + ((kb*16) ^ ((row & 7) << 4));
        *(f16x8*)dst = v;
    } else if (gid < 10240) {                 // W2 (128,128) -> 2 tiles
        int s = gid - 8192;
        int kb = s & 7, row = (s >> 3) & 127, kt = s >> 10;
        const float* src = W2 + row*128 + kt*64 + kb*8;
        f16x8 v;
        #pragma unroll
        for (int e = 0; e < 8; ++e) v[e] = (f16)src[e];
        char* dst = (char*)g_W2s + (size_t)kt*16384
                  + row*128 + ((kb*16) ^ ((row & 7) << 4));
        *(f16x8*)dst = v;
    } else if (gid < 14336) {                 // W3 (256,128) -> [nh:2][kt:2]
        int s = gid - 10240;
        int kb = s & 7, r256 = (s >> 3) & 255, kt = s >> 11;
        int nh = r256 >> 7, row = r256 & 127;
        const float* src = W3 + r256*128 + kt*64 + kb*8;
        f16x8 v;
        #pragma unroll
        for (int e = 0; e < 8; ++e) v[e] = (f16)src[e];
        char* dst = (char*)g_W3s + (size_t)(nh*2 + kt)*16384
                  + row*128 + ((kb*16) ^ ((row & 7) << 4));
        *(f16x8*)dst = v;
    }
}

// ---------------------------------------------------------------------------
// conv_x: X fp16 tile images (coalesced: 32 consecutive lanes = 1 KB)
// ---------------------------------------------------------------------------
__global__ __launch_bounds__(256) void conv_x(const float* __restrict__ padded)
{
    int gid = blockIdx.x*256 + threadIdx.x;   // 127*1024*32 = 4161536 exact
    int kq = gid & 31;
    int b  = (gid >> 5) & 1023;
    int t  = gid >> 15;
    const float* src = padded + (size_t)b*LE + t*E + kq*8;
    float4 v0 = *(const float4*)src;
    float4 v1 = *(const float4*)(src + 4);
    f16x8 v;
    v[0]=(f16)v0.x; v[1]=(f16)v0.y; v[2]=(f16)v0.z; v[3]=(f16)v0.w;
    v[4]=(f16)v1.x; v[5]=(f16)v1.y; v[6]=(f16)v1.z; v[7]=(f16)v1.w;
    int kt = kq >> 3, kb = kq & 7;
    int row = b & 63, mt16 = b >> 6;
    char* dst = (char*)g_Xs + (size_t)((t*16 + mt16)*4 + kt)*8192
              + row*128 + ((kb*16) ^ ((row & 7) << 4));
    *(f16x8*)dst = v;
}

// ---------------------------------------------------------------------------
// init: g_Hh[0] <- hidden image, out row 0 <- one-hot, flags+slots reset
// ---------------------------------------------------------------------------
__global__ __launch_bounds__(256) void init_kernel(
    const float* __restrict__ hidden, float* __restrict__ out)
{
    int i = blockIdx.x * 256 + threadIdx.x;
    if (i < 256) g_flags[i >> 5][i & 31].v = 0u;
    if (i < 8) g_slot[i] = 0u;
    if (i < B*H) {
        float hv = hidden[i];
        int b = i >> 9, j = i & 511;
        int mt = b >> 6, row = b & 63, kt = j >> 6, kk = j & 63;
        char* dst = (char*)g_Hh + (size_t)(mt*8 + kt)*8192
                  + row*128 + ((kk*2) ^ ((row & 7) << 4));
        *(f16*)dst = (f16)hv;
    }
    if (i < B*E) {
        int b = i >> 8, e = i & 255;
        out[b*LE + e] = (e == 0) ? 1.0f : 0.0f;
    }
}

// ---------------------------------------------------------------------------
// step_all: ROUND-11 WINNER SCHEDULE, unchanged. Only the sync mechanics
// changed: grp = physical XCD (s_getreg XCC_ID) + atomic slot for nt;
// flags are RELAXED (no wbl2/buffer_inv). grp/nt broadcast through the
// first bytes of lds[] (round-14 fix: separate __shared__ overflowed 160K).
// ---------------------------------------------------------------------------
__global__ __launch_bounds__(256, 1) void step_all()
{
    __shared__ __align__(16) char lds[163840];   // 96K B + 4 x 16K A slots
    char* Bb = lds;
    char* As = lds + 98304;
    f16 (*Hs)[16] = (f16 (*)[16])(As + 3*16384);      // aliases slot3

    const int tid  = threadIdx.x;
    const int lane = tid & 63;
    const int wv   = tid >> 6;          // 0..3
    const int l15  = lane & 15;
    const int p    = l15 & 3;
    const int klo  = (lane >> 4) << 4;

    // runtime grouping: grp = physical XCD, nt = slot within XCD.
    // Broadcast via lds[0..7] (B region, overwritten later by B staging).
    if (tid == 0) {
        uint32_t xcc;
        asm volatile("s_getreg_b32 %0, hwreg(HW_REG_XCC_ID)" : "=s"(xcc));
        xcc &= 7u;
        unsigned int slot = atomicAdd(&g_slot[xcc], 1u);
        ((int*)lds)[0] = (int)xcc;
        ((int*)lds)[1] = (int)(slot & 31u);
    }
    __syncthreads();
    const int grp = ((volatile int*)lds)[0];
    const int nt  = ((volatile int*)lds)[1];
    __syncthreads();   // all reads done before B staging overwrites lds[0..7]

    // ---- persistent B load (once): rows (nt&1)*64..+64 of itile nt>>1 ----
    {
        const char* src = (const char*)g_Ws + (size_t)(nt >> 1)*12*16384
                        + (size_t)(nt & 1)*64*128;
        #pragma unroll
        for (int it = 0; it < 24; ++it) {
            int c = wv*24 + it;             // 0..95 chunks of 1KB
            int kt = c >> 3, cc = c & 7;
            __builtin_amdgcn_global_load_lds(
                (gu32*)(src + (size_t)kt*16384 + cc*1024 + lane*16),
                (lu32*)(Bb + c*1024 + lane*16), 16, 0, 0);
        }
    }
    float4 bs4[4];
    #pragma unroll
    for (int n = 0; n < 4; ++n)
        bs4[n] = *(const float4*)&g_bsum[nt*64 + n*16 + (l15 >> 2)*4];

    float creg[2][4];
    #pragma unroll
    for (int m = 0; m < 2; ++m)
        #pragma unroll
        for (int n = 0; n < 4; ++n) creg[m][n] = 0.0f;

    asm volatile("s_waitcnt vmcnt(0)" ::: "memory");
    __syncthreads();

    auto stageA = [&](int t_, int kt_, int slot) {
        char* dst = As + slot*16384;
        #pragma unroll
        for (int it = 0; it < 4; ++it) {
            int c = wv*4 + it;              // 0..15 chunks of 1KB (16 KB)
            int sub = c >> 3, cc = c & 7;
            const char* src = (kt_ < 4)
                ? (const char*)g_Xs + (size_t)((t_*16 + grp*2 + sub)*4 + kt_)*8192
                : (const char*)g_Hh + (size_t)((t_*16 + grp*2 + sub)*8 + (kt_-4))*8192;
            __builtin_amdgcn_global_load_lds(
                (gu32*)(src + cc*1024 + lane*16),
                (lu32*)(dst + c*1024 + lane*16), 16, 0, 0);
        }
    };

    // group wait: lane-parallel RELAXED polls; compiler fence on exit (no
    // buffer_inv -- same-XCD L2 + first-touch h addresses make it safe)
    auto bar_wait = [&](unsigned int target) {
        if (tid < 64) {
            for (;;) {
                unsigned int v = __hip_atomic_load(&g_flags[grp][lane & 31].v,
                                   __ATOMIC_RELAXED, __HIP_MEMORY_SCOPE_AGENT);
                if (__all(v >= target)) break;
                __builtin_amdgcn_s_sleep(1);
            }
        }
        asm volatile("" ::: "memory");
        __syncthreads();
    };

    // prologue: X(0) kt0 -> S0, kt1 -> S1
    stageA(0, 0, 0);
    stageA(0, 1, 1);

    #pragma unroll 1
    for (int t = 0; t < 127; ++t) {
        stageA(t, 2, 2);
        stageA(t, 3, 3);
        f32x4 acc[2][4];
        #pragma unroll
        for (int m = 0; m < 2; ++m)
            #pragma unroll
            for (int n = 0; n < 4; ++n) acc[m][n] = (f32x4){0.f,0.f,0.f,0.f};

        #pragma unroll
        for (int kt = 0; kt < 12; ++kt) {
            // ONE barrier per kt: wait this kt's stage, sync slot reuse
            if (kt == 0)      asm volatile("s_waitcnt vmcnt(12)\n\ts_barrier" ::: "memory");
            else if (kt == 1) asm volatile("s_waitcnt vmcnt(8)\n\ts_barrier" ::: "memory");
            else if (kt == 2) asm volatile("s_waitcnt vmcnt(4)\n\ts_barrier" ::: "memory");
            else if (kt == 3) asm volatile("s_waitcnt vmcnt(0)\n\ts_barrier" ::: "memory");
            else              asm volatile("s_waitcnt vmcnt(8)\n\ts_barrier" ::: "memory");
            const char* Ar = As + (kt & 3)*16384;
            const char* Br = Bb + kt*8192;
            #pragma unroll
            for (int kkl = 0; kkl < 2; ++kkl) {
                const int kb = kkl*64 + klo;
                f16x8 a[2], b[4];
                #pragma unroll
                for (int m = 0; m < 2; ++m) {
                    int r = wv*32 + m*16 + l15;
                    a[m] = *(const f16x8*)(Ar + (r >> 6)*8192 + (r & 63)*128
                                           + (kb ^ ((r & 7) << 4)));
                }
                #pragma unroll
                for (int n = 0; n < 4; ++n) {
                    int r = n*16 + l15;
                    b[n] = *(const f16x8*)(Br + r*128 + (kb ^ ((r & 7) << 4)));
                }
                #pragma unroll
                for (int m = 0; m < 2; ++m)
                    #pragma unroll
                    for (int n = 0; n < 4; ++n)
                        acc[m][n] = __builtin_amdgcn_mfma_f32_16x16x32_f16(
                            a[m], b[n], acc[m][n], 0, 0, 0);
            }
            // end-of-kt staging: slot (kt+3)%4, last read at kt-1 (covered by
            // this kt's top barrier)
            if (kt == 3) {
                bar_wait((unsigned)t);             // h(t) visible (same-XCD L2)
                stageA(t, 4, 0); stageA(t, 5, 1); stageA(t, 6, 2);
            }
            if (kt == 4)  stageA(t, 7, 3);
            if (kt == 5)  stageA(t, 8, 0);
            if (kt == 6)  stageA(t, 9, 1);
            if (kt == 7)  stageA(t, 10, 2);
            if (kt == 8)  stageA(t, 11, 3);
            if (kt == 9)  stageA(t + 1, 0, 0);     // X(t+1); g_Xs padded
            if (kt == 10) stageA(t + 1, 1, 1);
        }

        // epilogue: barrier (slot3 reads consumed) -> transpose -> cell ->
        // Hs (aliases slot3) -> coalesced store
        asm volatile("s_barrier" ::: "memory");
        #pragma unroll
        for (int m = 0; m < 2; ++m)
            #pragma unroll
            for (int n = 0; n < 4; ++n) {
                float v0 = acc[m][n][0], v1 = acc[m][n][1];
                float v2 = acc[m][n][2], v3 = acc[m][n][3];
                float s, r;
                s = (p & 1) ? v0 : v1; r = __shfl_xor(s, 1); if (p & 1) v0 = r; else v1 = r;
                s = (p & 1) ? v2 : v3; r = __shfl_xor(s, 1); if (p & 1) v2 = r; else v3 = r;
                s = (p & 2) ? v0 : v2; r = __shfl_xor(s, 2); if (p & 2) v0 = r; else v2 = r;
                s = (p & 2) ? v1 : v3; r = __shfl_xor(s, 2); if (p & 2) v1 = r; else v3 = r;
                float iv = fsigm(v0 + bs4[n].x);
                float fv = fsigm(v1 + bs4[n].y);
                float gg = ftanh(v2 + bs4[n].z);
                float ov = fsigm(v3 + bs4[n].w);
                float cv = fv * creg[m][n] + iv * gg;
                creg[m][n] = cv;
                float hv = ov * ftanh(cv);
                int rowl = wv*32 + m*16 + ((lane >> 4) << 2) + p;   // 0..127
                int coll = n*4 + (l15 >> 2);                        // 0..15
                Hs[rowl][coll] = (f16)hv;
            }
        __syncthreads();
        // coalesced h store: ONE 16B store per thread (write-through -> L2)
        {
            char* hout = (char*)g_Hh + (size_t)(t + 1)*16*8*8192;
            int rowl = tid >> 1, half = tid & 1;
            int row = grp*128 + rowl;
            int jg  = nt*16 + half*8;
            f16x8 hv8 = *(const f16x8*)(&Hs[rowl][half*8]);
            char* hd = hout + (size_t)((row >> 6)*8 + (jg >> 6))*8192
                     + (row & 63)*128 + (((jg & 63)*2) ^ ((row & 7) << 4));
            *(f16x8*)hd = hv8;
        }
        asm volatile("s_waitcnt vmcnt(0)" ::: "memory");  // h complete in L2
        __syncthreads();
        if (tid == 0)
            __hip_atomic_store(&g_flags[grp][nt].v, (unsigned)(t + 1),
                               __ATOMIC_RELAXED, __HIP_MEMORY_SCOPE_AGENT);
    }
}

// ---------------------------------------------------------------------------
// mlp_all: batched 3-layer MLP for ALL tokens (round-4 proven structure).
// Block bi: tok = 1 + bi/16 (reads g_Hh[tok]), rows [mt*64,+64), mt = bi&15.
// ---------------------------------------------------------------------------
__global__ __launch_bounds__(256) void mlp_all(
    const float* __restrict__ b1, const float* __restrict__ b2,
    const float* __restrict__ b3, float* __restrict__ out)
{
    __shared__ char lds[65536];
    char* Wb = lds;            // 2 x 16384
    char* Ab = lds + 32768;    // 2 x 8192 (later Z2)
    char* Z1 = lds + 49152;    // 16384
    const int tid  = threadIdx.x;
    const int lane = tid & 63;
    const int w    = tid >> 6;
    const int bi   = blockIdx.x;
    const int tok  = 1 + (bi >> 4);
    const int mt   = bi & 15;
    const char* gH = (const char*)g_Hh + (size_t)(tok*16 + mt)*8*8192;
    float* outb = out + (size_t)(mt*64)*LE + (size_t)tok*E;

    float b1v[2], b2v[2], b3v[2][2];
    #pragma unroll
    for (int n = 0; n < 2; ++n) {
        int col = w*32 + n*16 + (lane & 15);
        b1v[n] = b1[col]; b2v[n] = b2[col];
        b3v[0][n] = b3[col]; b3v[1][n] = b3[128 + col];
    }
    const int kb0_0 = ((lane >> 4) << 4);

    f32x4 acc[4][2];
    #pragma unroll
    for (int m = 0; m < 4; ++m) { acc[m][0] = (f32x4){0,0,0,0}; acc[m][1] = (f32x4){0,0,0,0}; }

    #pragma unroll
    for (int it = 0; it < 2; ++it) {
        int c = w*2 + it;
        __builtin_amdgcn_global_load_lds((gu32*)(gH + c*1024 + lane*16),
                                         (lu32*)(Ab + c*1024 + lane*16), 16, 0, 0);
    }
    #pragma unroll
    for (int it = 0; it < 4; ++it) {
        int c = w*4 + it;
        __builtin_amdgcn_global_load_lds((gu32*)((const char*)g_W1s + c*1024 + lane*16),
                                         (lu32*)(Wb + c*1024 + lane*16), 16, 0, 0);
    }
    __syncthreads();

    for (int kt = 0; kt < 8; ++kt) {
        const int cur = kt & 1;
        if (kt < 7) {
            const char* gA = gH + (size_t)(kt+1)*8192;
            const char* gW = (const char*)g_W1s + (size_t)(kt+1)*16384;
            char* dA = Ab + (cur^1)*8192;
            char* dW = Wb + (cur^1)*16384;
            #pragma unroll
            for (int it = 0; it < 2; ++it) {
                int c = w*2 + it;
                __builtin_amdgcn_global_load_lds((gu32*)(gA + c*1024 + lane*16),
                                                 (lu32*)(dA + c*1024 + lane*16), 16, 0, 0);
            }
            #pragma unroll
            for (int it = 0; it < 4; ++it) {
                int c = w*4 + it;
                __builtin_amdgcn_global_load_lds((gu32*)(gW + c*1024 + lane*16),
                                                 (lu32*)(dW + c*1024 + lane*16), 16, 0, 0);
            }
        }
        const char* Ar = Ab + cur*8192;
        const char* Br = Wb + cur*16384;
        #pragma unroll
        for (int kk = 0; kk < 2; ++kk) {
            const int kb0 = kk*64 + kb0_0;
            f16x8 a[4], b[2];
            #pragma unroll
            for (int m = 0; m < 4; ++m) {
                int ar = m*16 + (lane & 15);
                a[m] = *(const f16x8*)(Ar + ar*128 + (kb0 ^ ((ar & 7) << 4)));
            }
            #pragma unroll
            for (int n = 0; n < 2; ++n) {
                int br = w*32 + n*16 + (lane & 15);
                b[n] = *(const f16x8*)(Br + br*128 + (kb0 ^ ((br & 7) << 4)));
            }
            #pragma unroll
            for (int m = 0; m < 4; ++m)
                #pragma unroll
                for (int n = 0; n < 2; ++n)
                    acc[m][n] = __builtin_amdgcn_mfma_f32_16x16x32_f16(a[m], b[n], acc[m][n], 0, 0, 0);
        }
        __syncthreads();
    }

    #pragma unroll
    for (int m = 0; m < 4; ++m)
        #pragma unroll
        for (int n = 0; n < 2; ++n)
            #pragma unroll
            for (int i = 0; i < 4; ++i) {
                int row = m*16 + ((lane >> 4) << 2) + i;
                int col = w*32 + n*16 + (lane & 15);
                float v = fmaxf(acc[m][n][i] + b1v[n], 0.0f);
                *(f16*)(Z1 + (col >> 6)*8192 + row*128
                        + (((col & 63)*2) ^ ((row & 7) << 4))) = (f16)v;
            }
    __syncthreads();

    #pragma unroll
    for (int it = 0; it < 8; ++it) {
        int c = w*8 + it;
        __builtin_amdgcn_global_load_lds((gu32*)((const char*)g_W2s + c*1024 + lane*16),
                                         (lu32*)(Wb + c*1024 + lane*16), 16, 0, 0);
    }
    __syncthreads();
    #pragma unroll
    for (int m = 0; m < 4; ++m) { acc[m][0] = (f32x4){0,0,0,0}; acc[m][1] = (f32x4){0,0,0,0}; }
    #pragma unroll
    for (int kt = 0; kt < 2; ++kt)
        #pragma unroll
        for (int kk = 0; kk < 2; ++kk) {
            const int kb0 = kk*64 + kb0_0;
            f16x8 a[4], b[2];
            #pragma unroll
            for (int m = 0; m < 4; ++m) {
                int ar = m*16 + (lane & 15);
                a[m] = *(const f16x8*)(Z1 + kt*8192 + ar*128 + (kb0 ^ ((ar & 7) << 4)));
            }
            #pragma unroll
            for (int n = 0; n < 2; ++n) {
                int br = w*32 + n*16 + (lane & 15);
                b[n] = *(const f16x8*)(Wb + kt*16384 + br*128 + (kb0 ^ ((br & 7) << 4)));
            }
            #pragma unroll
            for (int m = 0; m < 4; ++m)
                #pragma unroll
                for (int n = 0; n < 2; ++n)
                    acc[m][n] = __builtin_amdgcn_mfma_f32_16x16x32_f16(a[m], b[n], acc[m][n], 0, 0, 0);
        }
    __syncthreads();

    #pragma unroll
    for (int m = 0; m < 4; ++m)
        #pragma unroll
        for (int n = 0; n < 2; ++n)
            #pragma unroll
            for (int i = 0; i < 4; ++i) {
                int row = m*16 + ((lane >> 4) << 2) + i;
                int col = w*32 + n*16 + (lane & 15);
                float v = fmaxf(acc[m][n][i] + b2v[n], 0.0f);
                *(f16*)(Ab + (col >> 6)*8192 + row*128
                        + (((col & 63)*2) ^ ((row & 7) << 4))) = (f16)v;
            }
    __syncthreads();

    #pragma unroll
    for (int nh = 0; nh < 2; ++nh) {
        #pragma unroll
        for (int it = 0; it < 8; ++it) {
            int c = w*8 + it;
            __builtin_amdgcn_global_load_lds(
                (gu32*)((const char*)g_W3s + (size_t)nh*32768 + c*1024 + lane*16),
                (lu32*)(Wb + c*1024 + lane*16), 16, 0, 0);
        }
        __syncthreads();
        #pragma unroll
        for (int m = 0; m < 4; ++m) { acc[m][0] = (f32x4){0,0,0,0}; acc[m][1] = (f32x4){0,0,0,0}; }
        #pragma unroll
        for (int kt = 0; kt < 2; ++kt)
            #pragma unroll
            for (int kk = 0; kk < 2; ++kk) {
                const int kb0 = kk*64 + kb0_0;
                f16x8 a[4], b[2];
                #pragma unroll
                for (int m = 0; m < 4; ++m) {
                    int ar = m*16 + (lane & 15);
                    a[m] = *(const f16x8*)(Ab + kt*8192 + ar*128 + (kb0 ^ ((ar & 7) << 4)));
                }
                #pragma unroll
                for (int n = 0; n < 2; ++n) {
                    int br = w*32 + n*16 + (lane & 15);
                    b[n] = *(const f16x8*)(Wb + kt*16384 + br*128 + (kb0 ^ ((br & 7) << 4)));
                }
                #pragma unroll
                for (int m = 0; m < 4; ++m)
                    #pragma unroll
                    for (int n = 0; n < 2; ++n)
                        acc[m][n] = __builtin_amdgcn_mfma_f32_16x16x32_f16(a[m], b[n], acc[m][n], 0, 0, 0);
            }
        #pragma unroll
        for (int m = 0; m < 4; ++m)
            #pragma unroll
            for (int n = 0; n < 2; ++n)
                #pragma unroll
                for (int i = 0; i < 4; ++i) {
                    int row = m*16 + ((lane >> 4) << 2) + i;
                    int col = nh*128 + w*32 + n*16 + (lane & 15);
                    outb[(size_t)row*LE + col] = acc[m][n][i] + b3v[nh][n];
                }
        __syncthreads();
    }
}

// ---------------------------------------------------------------------------
extern "C" void kernel_launch(void* const* d_in, const int* in_sizes, int n_in,
                              void* d_out, int out_size, void* d_ws, size_t ws_size,
                              hipStream_t stream) {
    (void)in_sizes; (void)n_in; (void)out_size; (void)d_ws; (void)ws_size;
    const float* hidden = (const float*)d_in[0];
    const float* padded = (const float*)d_in[1];
    const float* W_ih   = (const float*)d_in[2];
    const float* W_hh   = (const float*)d_in[3];
    const float* b_ih   = (const float*)d_in[4];
    const float* b_hh   = (const float*)d_in[5];
    const float* W1     = (const float*)d_in[6];
    const float* b1     = (const float*)d_in[7];
    const float* W2     = (const float*)d_in[8];
    const float* b2     = (const float*)d_in[9];
    const float* W3     = (const float*)d_in[10];
    const float* b3     = (const float*)d_in[11];
    float* out = (float*)d_out;

    conv_w<<<768, 256, 0, stream>>>(W_ih, W_hh, b_ih, b_hh);
    conv_mlp<<<56, 256, 0, stream>>>(W1, W2, W3);
    conv_x<<<16256, 256, 0, stream>>>(padded);
    init_kernel<<<2048, 256, 0, stream>>>(hidden, out);
    step_all<<<256, 256, 0, stream>>>();
    mlp_all<<<2032, 256, 0, stream>>>(b1, b2, b3, out);
}

// Round 16
// 834.085 us; speedup vs baseline: 2.6607x; 1.0473x over previous
//
#include <hip/hip_runtime.h>
#include <math.h>
#include <stdint.h>

#define B 1024
#define H 512
#define E 256
#define L 128
#define LE (L*E)   // 32768

typedef _Float16 f16;
typedef _Float16 f16x8 __attribute__((ext_vector_type(8)));
typedef float f32x4 __attribute__((ext_vector_type(4)));
typedef const __attribute__((address_space(1))) uint32_t gu32;
typedef __attribute__((address_space(3))) uint32_t lu32;

// ---------------------------------------------------------------------------
// Persistent state in module device globals. Everything rewritten every call.
// ---------------------------------------------------------------------------
__device__ __align__(16) f16 g_Xs[128*16*4*4096];   // X images [t:128 pad][mt16][kt:4] 64x64
__device__ __align__(16) f16 g_Hh[128*16*8*4096];   // h(t) images, t=0..127 (134 MB)
__device__ __align__(16) f16 g_Ws[16*12*8192];      // gates W' [itile:16][kt:12] 128x64
__device__ __align__(16) f16 g_W1s[8*8192];         // W1' [kt:8] 128x64
__device__ __align__(16) f16 g_W2s[2*8192];         // W2' [kt:2] 128x64
__device__ __align__(16) f16 g_W3s[4*8192];         // W3' [nh:2][kt:2] 128x64
__device__ __align__(16) float g_bsum[2048];        // b_ih+b_hh, n=j*4+g order

// Flag array (one line per flag) + per-XCD slot counters. Groups are
// PHYSICAL XCDs (grp = HW_REG_XCC_ID): h-exchange lives in one shared L2,
// so no release-wbl2 / acquire-buffer_inv per step (round-15 win). Flags
// are RELAXED agent atomics.
struct __align__(128) Flag { unsigned int v; unsigned int pad[31]; };
__device__ Flag g_flags[8][32];
__device__ unsigned int g_slot[8];

__device__ __forceinline__ float fsigm(float x) {
    return __builtin_amdgcn_rcpf(1.0f + __expf(-x));
}
__device__ __forceinline__ float ftanh(float x) {
    return 2.0f * __builtin_amdgcn_rcpf(1.0f + __expf(-2.0f * x)) - 1.0f;
}

// ---------------------------------------------------------------------------
// conv_w: gates W' fp16 tile images (gate-interleaved n=j*4+g) + bias sums
// ---------------------------------------------------------------------------
__global__ __launch_bounds__(256) void conv_w(
    const float* __restrict__ W_ih, const float* __restrict__ W_hh,
    const float* __restrict__ b_ih, const float* __restrict__ b_hh)
{
    int gid = blockIdx.x*256 + threadIdx.x;   // 196608
    int kb  = gid & 7;
    int r1  = gid >> 3;
    int row = r1 & 127;
    int r2  = r1 >> 7;
    int kt  = r2 % 12;
    int nt  = r2 / 12;
    int n = nt*128 + row;
    int g = n & 3, j = n >> 2;
    int wrow = g*512 + j;
    int k = kt*64 + kb*8;
    const float* src = (k < 256) ? (W_ih + wrow*256 + k)
                                 : (W_hh + wrow*512 + (k - 256));
    f16x8 v;
    #pragma unroll
    for (int e = 0; e < 8; ++e) v[e] = (f16)src[e];
    char* dst = (char*)g_Ws + (size_t)(nt*12 + kt)*16384
              + row*128 + ((kb*16) ^ ((row & 7) << 4));
    *(f16x8*)dst = v;
    if (gid < 2048) {
        int gg = gid & 3, jj = gid >> 2;
        g_bsum[gid] = b_ih[gg*512 + jj] + b_hh[gg*512 + jj];
    }
}

// ---------------------------------------------------------------------------
// conv_mlp: W1/W2/W3 fp16 tile images
// ---------------------------------------------------------------------------
__global__ __launch_bounds__(256) void conv_mlp(
    const float* __restrict__ W1, const float* __restrict__ W2,
    const float* __restrict__ W3)
{
    int gid = blockIdx.x*256 + threadIdx.x;   // 14336
    if (gid < 8192) {                         // W1 (128,512) -> 8 tiles
        int s = gid;
        int kb = s & 7, row = (s >> 3) & 127, kt = s >> 10;
        const float* src = W1 + row*512 + kt*64 + kb*8;
        f16x8 v;
        #pragma unroll
        for (int e = 0; e < 8; ++e) v[e] = (f16)src[e];
        char* dst = (char*)g_W1s + (size_t)kt*16384
                  + row*128 + ((kb*16) ^ ((row & 7) << 4));
        *(f16x8*)dst = v;
    } else if (gid < 10240) {                 // W2 (128,128) -> 2 tiles
        int s = gid - 8192;
        int kb = s & 7, row = (s >> 3) & 127, kt = s >> 10;
        const float* src = W2 + row*128 + kt*64 + kb*8;
        f16x8 v;
        #pragma unroll
        for (int e = 0; e < 8; ++e) v[e] = (f16)src[e];
        char* dst = (char*)g_W2s + (size_t)kt*16384
                  + row*128 + ((kb*16) ^ ((row & 7) << 4));
        *(f16x8*)dst = v;
    } else if (gid < 14336) {                 // W3 (256,128) -> [nh:2][kt:2]
        int s = gid - 10240;
        int kb = s & 7, r256 = (s >> 3) & 255, kt = s >> 11;
        int nh = r256 >> 7, row = r256 & 127;
        const float* src = W3 + r256*128 + kt*64 + kb*8;
        f16x8 v;
        #pragma unroll
        for (int e = 0; e < 8; ++e) v[e] = (f16)src[e];
        char* dst = (char*)g_W3s + (size_t)(nh*2 + kt)*16384
                  + row*128 + ((kb*16) ^ ((row & 7) << 4));
        *(f16x8*)dst = v;
    }
}

// ---------------------------------------------------------------------------
// conv_x: X fp16 tile images (coalesced: 32 consecutive lanes = 1 KB)
// ---------------------------------------------------------------------------
__global__ __launch_bounds__(256) void conv_x(const float* __restrict__ padded)
{
    int gid = blockIdx.x*256 + threadIdx.x;   // 127*1024*32 = 4161536 exact
    int kq = gid & 31;
    int b  = (gid >> 5) & 1023;
    int t  = gid >> 15;
    const float* src = padded + (size_t)b*LE + t*E + kq*8;
    float4 v0 = *(const float4*)src;
    float4 v1 = *(const float4*)(src + 4);
    f16x8 v;
    v[0]=(f16)v0.x; v[1]=(f16)v0.y; v[2]=(f16)v0.z; v[3]=(f16)v0.w;
    v[4]=(f16)v1.x; v[5]=(f16)v1.y; v[6]=(f16)v1.z; v[7]=(f16)v1.w;
    int kt = kq >> 3, kb = kq & 7;
    int row = b & 63, mt16 = b >> 6;
    char* dst = (char*)g_Xs + (size_t)((t*16 + mt16)*4 + kt)*8192
              + row*128 + ((kb*16) ^ ((row & 7) << 4));
    *(f16x8*)dst = v;
}

// ---------------------------------------------------------------------------
// init: g_Hh[0] <- hidden image, out row 0 <- one-hot, flags+slots reset
// ---------------------------------------------------------------------------
__global__ __launch_bounds__(256) void init_kernel(
    const float* __restrict__ hidden, float* __restrict__ out)
{
    int i = blockIdx.x * 256 + threadIdx.x;
    if (i < 256) g_flags[i >> 5][i & 31].v = 0u;
    if (i < 8) g_slot[i] = 0u;
    if (i < B*H) {
        float hv = hidden[i];
        int b = i >> 9, j = i & 511;
        int mt = b >> 6, row = b & 63, kt = j >> 6, kk = j & 63;
        char* dst = (char*)g_Hh + (size_t)(mt*8 + kt)*8192
                  + row*128 + ((kk*2) ^ ((row & 7) << 4));
        *(f16*)dst = (f16)hv;
    }
    if (i < B*E) {
        int b = i >> 8, e = i & 255;
        out[b*LE + e] = (e == 0) ? 1.0f : 0.0f;
    }
}

// ---------------------------------------------------------------------------
// step_all: round-15 winner + deeper prefetch schedule. Flag-wait moved to
// kt1-end; H stages spread one-per-kt-end (kt4@kt1 ... kt11@kt8); vmcnt is
// UNIFORM kt0->12 else->8 -- no vmcnt(0) drain anywhere in the kt loop.
// Slot-reuse audited: every restage hits a slot last read at kt-1 or older,
// covered by the kt-top barrier.
// ---------------------------------------------------------------------------
__global__ __launch_bounds__(256, 1) void step_all()
{
    __shared__ __align__(16) char lds[163840];   // 96K B + 4 x 16K A slots
    char* Bb = lds;
    char* As = lds + 98304;
    f16 (*Hs)[16] = (f16 (*)[16])(As + 3*16384);      // aliases slot3

    const int tid  = threadIdx.x;
    const int lane = tid & 63;
    const int wv   = tid >> 6;          // 0..3
    const int l15  = lane & 15;
    const int p    = l15 & 3;
    const int klo  = (lane >> 4) << 4;

    // runtime grouping: grp = physical XCD, nt = slot within XCD.
    // Broadcast via lds[0..7] (B region, overwritten later by B staging).
    if (tid == 0) {
        uint32_t xcc;
        asm volatile("s_getreg_b32 %0, hwreg(HW_REG_XCC_ID)" : "=s"(xcc));
        xcc &= 7u;
        unsigned int slot = atomicAdd(&g_slot[xcc], 1u);
        ((int*)lds)[0] = (int)xcc;
        ((int*)lds)[1] = (int)(slot & 31u);
    }
    __syncthreads();
    const int grp = ((volatile int*)lds)[0];
    const int nt  = ((volatile int*)lds)[1];
    __syncthreads();   // all reads done before B staging overwrites lds[0..7]

    // ---- persistent B load (once): rows (nt&1)*64..+64 of itile nt>>1 ----
    {
        const char* src = (const char*)g_Ws + (size_t)(nt >> 1)*12*16384
                        + (size_t)(nt & 1)*64*128;
        #pragma unroll
        for (int it = 0; it < 24; ++it) {
            int c = wv*24 + it;             // 0..95 chunks of 1KB
            int kt = c >> 3, cc = c & 7;
            __builtin_amdgcn_global_load_lds(
                (gu32*)(src + (size_t)kt*16384 + cc*1024 + lane*16),
                (lu32*)(Bb + c*1024 + lane*16), 16, 0, 0);
        }
    }
    float4 bs4[4];
    #pragma unroll
    for (int n = 0; n < 4; ++n)
        bs4[n] = *(const float4*)&g_bsum[nt*64 + n*16 + (l15 >> 2)*4];

    float creg[2][4];
    #pragma unroll
    for (int m = 0; m < 2; ++m)
        #pragma unroll
        for (int n = 0; n < 4; ++n) creg[m][n] = 0.0f;

    asm volatile("s_waitcnt vmcnt(0)" ::: "memory");
    __syncthreads();

    auto stageA = [&](int t_, int kt_, int slot) {
        char* dst = As + slot*16384;
        #pragma unroll
        for (int it = 0; it < 4; ++it) {
            int c = wv*4 + it;              // 0..15 chunks of 1KB (16 KB)
            int sub = c >> 3, cc = c & 7;
            const char* src = (kt_ < 4)
                ? (const char*)g_Xs + (size_t)((t_*16 + grp*2 + sub)*4 + kt_)*8192
                : (const char*)g_Hh + (size_t)((t_*16 + grp*2 + sub)*8 + (kt_-4))*8192;
            __builtin_amdgcn_global_load_lds(
                (gu32*)(src + cc*1024 + lane*16),
                (lu32*)(dst + c*1024 + lane*16), 16, 0, 0);
        }
    };

    // group wait: lane-parallel RELAXED polls; compiler fence on exit (no
    // buffer_inv -- same-XCD L2 + first-touch h addresses make it safe)
    auto bar_wait = [&](unsigned int target) {
        if (tid < 64) {
            for (;;) {
                unsigned int v = __hip_atomic_load(&g_flags[grp][lane & 31].v,
                                   __ATOMIC_RELAXED, __HIP_MEMORY_SCOPE_AGENT);
                if (__all(v >= target)) break;
                __builtin_amdgcn_s_sleep(1);
            }
        }
        asm volatile("" ::: "memory");
        __syncthreads();
    };

    // prologue: X(0) kt0 -> S0, kt1 -> S1
    stageA(0, 0, 0);
    stageA(0, 1, 1);

    #pragma unroll 1
    for (int t = 0; t < 127; ++t) {
        stageA(t, 2, 2);
        stageA(t, 3, 3);
        f32x4 acc[2][4];
        #pragma unroll
        for (int m = 0; m < 2; ++m)
            #pragma unroll
            for (int n = 0; n < 4; ++n) acc[m][n] = (f32x4){0.f,0.f,0.f,0.f};

        #pragma unroll
        for (int kt = 0; kt < 12; ++kt) {
            // ONE barrier per kt; uniform counted waits, never vmcnt(0)
            if (kt == 0) asm volatile("s_waitcnt vmcnt(12)\n\ts_barrier" ::: "memory");
            else         asm volatile("s_waitcnt vmcnt(8)\n\ts_barrier" ::: "memory");
            const char* Ar = As + (kt & 3)*16384;
            const char* Br = Bb + kt*8192;
            #pragma unroll
            for (int kkl = 0; kkl < 2; ++kkl) {
                const int kb = kkl*64 + klo;
                f16x8 a[2], b[4];
                #pragma unroll
                for (int m = 0; m < 2; ++m) {
                    int r = wv*32 + m*16 + l15;
                    a[m] = *(const f16x8*)(Ar + (r >> 6)*8192 + (r & 63)*128
                                           + (kb ^ ((r & 7) << 4)));
                }
                #pragma unroll
                for (int n = 0; n < 4; ++n) {
                    int r = n*16 + l15;
                    b[n] = *(const f16x8*)(Br + r*128 + (kb ^ ((r & 7) << 4)));
                }
                #pragma unroll
                for (int m = 0; m < 2; ++m)
                    #pragma unroll
                    for (int n = 0; n < 4; ++n)
                        acc[m][n] = __builtin_amdgcn_mfma_f32_16x16x32_f16(
                            a[m], b[n], acc[m][n], 0, 0, 0);
            }
            // end-of-kt staging: each restaged slot was last READ at kt-1 or
            // older (covered by this kt's top barrier). kt4 gets ~2.5 kt lead.
            if (kt == 1) { bar_wait((unsigned)t); stageA(t, 4, 0); }
            if (kt == 2)  stageA(t, 5, 1);
            if (kt == 3)  stageA(t, 6, 2);
            if (kt == 4)  stageA(t, 7, 3);
            if (kt == 5)  stageA(t, 8, 0);
            if (kt == 6)  stageA(t, 9, 1);
            if (kt == 7)  stageA(t, 10, 2);
            if (kt == 8)  stageA(t, 11, 3);
            if (kt == 9)  stageA(t + 1, 0, 0);     // X(t+1); g_Xs padded
            if (kt == 10) stageA(t + 1, 1, 1);
        }

        // epilogue: barrier (slot3 reads consumed) -> transpose -> cell ->
        // Hs (aliases slot3) -> coalesced store
        asm volatile("s_barrier" ::: "memory");
        #pragma unroll
        for (int m = 0; m < 2; ++m)
            #pragma unroll
            for (int n = 0; n < 4; ++n) {
                float v0 = acc[m][n][0], v1 = acc[m][n][1];
                float v2 = acc[m][n][2], v3 = acc[m][n][3];
                float s, r;
                s = (p & 1) ? v0 : v1; r = __shfl_xor(s, 1); if (p & 1) v0 = r; else v1 = r;
                s = (p & 1) ? v2 : v3; r = __shfl_xor(s, 1); if (p & 1) v2 = r; else v3 = r;
                s = (p & 2) ? v0 : v2; r = __shfl_xor(s, 2); if (p & 2) v0 = r; else v2 = r;
                s = (p & 2) ? v1 : v3; r = __shfl_xor(s, 2); if (p & 2) v1 = r; else v3 = r;
                float iv = fsigm(v0 + bs4[n].x);
                float fv = fsigm(v1 + bs4[n].y);
                float gg = ftanh(v2 + bs4[n].z);
                float ov = fsigm(v3 + bs4[n].w);
                float cv = fv * creg[m][n] + iv * gg;
                creg[m][n] = cv;
                float hv = ov * ftanh(cv);
                int rowl = wv*32 + m*16 + ((lane >> 4) << 2) + p;   // 0..127
                int coll = n*4 + (l15 >> 2);                        // 0..15
                Hs[rowl][coll] = (f16)hv;
            }
        __syncthreads();
        // coalesced h store: ONE 16B store per thread (write-through -> L2)
        {
            char* hout = (char*)g_Hh + (size_t)(t + 1)*16*8*8192;
            int rowl = tid >> 1, half = tid & 1;
            int row = grp*128 + rowl;
            int jg  = nt*16 + half*8;
            f16x8 hv8 = *(const f16x8*)(&Hs[rowl][half*8]);
            char* hd = hout + (size_t)((row >> 6)*8 + (jg >> 6))*8192
                     + (row & 63)*128 + (((jg & 63)*2) ^ ((row & 7) << 4));
            *(f16x8*)hd = hv8;
        }
        asm volatile("s_waitcnt vmcnt(0)" ::: "memory");  // h complete in L2
        __syncthreads();
        if (tid == 0)
            __hip_atomic_store(&g_flags[grp][nt].v, (unsigned)(t + 1),
                               __ATOMIC_RELAXED, __HIP_MEMORY_SCOPE_AGENT);
    }
}

// ---------------------------------------------------------------------------
// mlp_all: batched 3-layer MLP for ALL tokens (round-4 proven structure).
// Block bi: tok = 1 + bi/16 (reads g_Hh[tok]), rows [mt*64,+64), mt = bi&15.
// ---------------------------------------------------------------------------
__global__ __launch_bounds__(256) void mlp_all(
    const float* __restrict__ b1, const float* __restrict__ b2,
    const float* __restrict__ b3, float* __restrict__ out)
{
    __shared__ char lds[65536];
    char* Wb = lds;            // 2 x 16384
    char* Ab = lds + 32768;    // 2 x 8192 (later Z2)
    char* Z1 = lds + 49152;    // 16384
    const int tid  = threadIdx.x;
    const int lane = tid & 63;
    const int w    = tid >> 6;
    const int bi   = blockIdx.x;
    const int tok  = 1 + (bi >> 4);
    const int mt   = bi & 15;
    const char* gH = (const char*)g_Hh + (size_t)(tok*16 + mt)*8*8192;
    float* outb = out + (size_t)(mt*64)*LE + (size_t)tok*E;

    float b1v[2], b2v[2], b3v[2][2];
    #pragma unroll
    for (int n = 0; n < 2; ++n) {
        int col = w*32 + n*16 + (lane & 15);
        b1v[n] = b1[col]; b2v[n] = b2[col];
        b3v[0][n] = b3[col]; b3v[1][n] = b3[128 + col];
    }
    const int kb0_0 = ((lane >> 4) << 4);

    f32x4 acc[4][2];
    #pragma unroll
    for (int m = 0; m < 4; ++m) { acc[m][0] = (f32x4){0,0,0,0}; acc[m][1] = (f32x4){0,0,0,0}; }

    #pragma unroll
    for (int it = 0; it < 2; ++it) {
        int c = w*2 + it;
        __builtin_amdgcn_global_load_lds((gu32*)(gH + c*1024 + lane*16),
                                         (lu32*)(Ab + c*1024 + lane*16), 16, 0, 0);
    }
    #pragma unroll
    for (int it = 0; it < 4; ++it) {
        int c = w*4 + it;
        __builtin_amdgcn_global_load_lds((gu32*)((const char*)g_W1s + c*1024 + lane*16),
                                         (lu32*)(Wb + c*1024 + lane*16), 16, 0, 0);
    }
    __syncthreads();

    for (int kt = 0; kt < 8; ++kt) {
        const int cur = kt & 1;
        if (kt < 7) {
            const char* gA = gH + (size_t)(kt+1)*8192;
            const char* gW = (const char*)g_W1s + (size_t)(kt+1)*16384;
            char* dA = Ab + (cur^1)*8192;
            char* dW = Wb + (cur^1)*16384;
            #pragma unroll
            for (int it = 0; it < 2; ++it) {
                int c = w*2 + it;
                __builtin_amdgcn_global_load_lds((gu32*)(gA + c*1024 + lane*16),
                                                 (lu32*)(dA + c*1024 + lane*16), 16, 0, 0);
            }
            #pragma unroll
            for (int it = 0; it < 4; ++it) {
                int c = w*4 + it;
                __builtin_amdgcn_global_load_lds((gu32*)(gW + c*1024 + lane*16),
                                                 (lu32*)(dW + c*1024 + lane*16), 16, 0, 0);
            }
        }
        const char* Ar = Ab + cur*8192;
        const char* Br = Wb + cur*16384;
        #pragma unroll
        for (int kk = 0; kk < 2; ++kk) {
            const int kb0 = kk*64 + kb0_0;
            f16x8 a[4], b[2];
            #pragma unroll
            for (int m = 0; m < 4; ++m) {
                int ar = m*16 + (lane & 15);
                a[m] = *(const f16x8*)(Ar + ar*128 + (kb0 ^ ((ar & 7) << 4)));
            }
            #pragma unroll
            for (int n = 0; n < 2; ++n) {
                int br = w*32 + n*16 + (lane & 15);
                b[n] = *(const f16x8*)(Br + br*128 + (kb0 ^ ((br & 7) << 4)));
            }
            #pragma unroll
            for (int m = 0; m < 4; ++m)
                #pragma unroll
                for (int n = 0; n < 2; ++n)
                    acc[m][n] = __builtin_amdgcn_mfma_f32_16x16x32_f16(a[m], b[n], acc[m][n], 0, 0, 0);
        }
        __syncthreads();
    }

    #pragma unroll
    for (int m = 0; m < 4; ++m)
        #pragma unroll
        for (int n = 0; n < 2; ++n)
            #pragma unroll
            for (int i = 0; i < 4; ++i) {
                int row = m*16 + ((lane >> 4) << 2) + i;
                int col = w*32 + n*16 + (lane & 15);
                float v = fmaxf(acc[m][n][i] + b1v[n], 0.0f);
                *(f16*)(Z1 + (col >> 6)*8192 + row*128
                        + (((col & 63)*2) ^ ((row & 7) << 4))) = (f16)v;
            }
    __syncthreads();

    #pragma unroll
    for (int it = 0; it < 8; ++it) {
        int c = w*8 + it;
        __builtin_amdgcn_global_load_lds((gu32*)((const char*)g_W2s + c*1024 + lane*16),
                                         (lu32*)(Wb + c*1024 + lane*16), 16, 0, 0);
    }
    __syncthreads();
    #pragma unroll
    for (int m = 0; m < 4; ++m) { acc[m][0] = (f32x4){0,0,0,0}; acc[m][1] = (f32x4){0,0,0,0}; }
    #pragma unroll
    for (int kt = 0; kt < 2; ++kt)
        #pragma unroll
        for (int kk = 0; kk < 2; ++kk) {
            const int kb0 = kk*64 + kb0_0;
            f16x8 a[4], b[2];
            #pragma unroll
            for (int m = 0; m < 4; ++m) {
                int ar = m*16 + (lane & 15);
                a[m] = *(const f16x8*)(Z1 + kt*8192 + ar*128 + (kb0 ^ ((ar & 7) << 4)));
            }
            #pragma unroll
            for (int n = 0; n < 2; ++n) {
                int br = w*32 + n*16 + (lane & 15);
                b[n] = *(const f16x8*)(Wb + kt*16384 + br*128 + (kb0 ^ ((br & 7) << 4)));
            }
            #pragma unroll
            for (int m = 0; m < 4; ++m)
                #pragma unroll
                for (int n = 0; n < 2; ++n)
                    acc[m][n] = __builtin_amdgcn_mfma_f32_16x16x32_f16(a[m], b[n], acc[m][n], 0, 0, 0);
        }
    __syncthreads();

    #pragma unroll
    for (int m = 0; m < 4; ++m)
        #pragma unroll
        for (int n = 0; n < 2; ++n)
            #pragma unroll
            for (int i = 0; i < 4; ++i) {
                int row = m*16 + ((lane >> 4) << 2) + i;
                int col = w*32 + n*16 + (lane & 15);
                float v = fmaxf(acc[m][n][i] + b2v[n], 0.0f);
                *(f16*)(Ab + (col >> 6)*8192 + row*128
                        + (((col & 63)*2) ^ ((row & 7) << 4))) = (f16)v;
            }
    __syncthreads();

    #pragma unroll
    for (int nh = 0; nh < 2; ++nh) {
        #pragma unroll
        for (int it = 0; it < 8; ++it) {
            int c = w*8 + it;
            __builtin_amdgcn_global_load_lds(
                (gu32*)((const char*)g_W3s + (size_t)nh*32768 + c*1024 + lane*16),
                (lu32*)(Wb + c*1024 + lane*16), 16, 0, 0);
        }
        __syncthreads();
        #pragma unroll
        for (int m = 0; m < 4; ++m) { acc[m][0] = (f32x4){0,0,0,0}; acc[m][1] = (f32x4){0,0,0,0}; }
        #pragma unroll
        for (int kt = 0; kt < 2; ++kt)
            #pragma unroll
            for (int kk = 0; kk < 2; ++kk) {
                const int kb0 = kk*64 + kb0_0;
                f16x8 a[4], b[2];
                #pragma unroll
                for (int m = 0; m < 4; ++m) {
                    int ar = m*16 + (lane & 15);
                    a[m] = *(const f16x8*)(Ab + kt*8192 + ar*128 + (kb0 ^ ((ar & 7) << 4)));
                }
                #pragma unroll
                for (int n = 0; n < 2; ++n) {
                    int br = w*32 + n*16 + (lane & 15);
                    b[n] = *(const f16x8*)(Wb + kt*16384 + br*128 + (kb0 ^ ((br & 7) << 4)));
                }
                #pragma unroll
                for (int m = 0; m < 4; ++m)
                    #pragma unroll
                    for (int n = 0; n < 2; ++n)
                        acc[m][n] = __builtin_amdgcn_mfma_f32_16x16x32_f16(a[m], b[n], acc[m][n], 0, 0, 0);
            }
        #pragma unroll
        for (int m = 0; m < 4; ++m)
            #pragma unroll
            for (int n = 0; n < 2; ++n)
                #pragma unroll
                for (int i = 0; i < 4; ++i) {
                    int row = m*16 + ((lane >> 4) << 2) + i;
                    int col = nh*128 + w*32 + n*16 + (lane & 15);
                    outb[(size_t)row*LE + col] = acc[m][n][i] + b3v[nh][n];
                }
        __syncthreads();
    }
}

// ---------------------------------------------------------------------------
extern "C" void kernel_launch(void* const* d_in, const int* in_sizes, int n_in,
                              void* d_out, int out_size, void* d_ws, size_t ws_size,
                              hipStream_t stream) {
    (void)in_sizes; (void)n_in; (void)out_size; (void)d_ws; (void)ws_size;
    const float* hidden = (const float*)d_in[0];
    const float* padded = (const float*)d_in[1];
    const float* W_ih   = (const float*)d_in[2];
    const float* W_hh   = (const float*)d_in[3];
    const float* b_ih   = (const float*)d_in[4];
    const float* b_hh   = (const float*)d_in[5];
    const float* W1     = (const float*)d_in[6];
    const float* b1     = (const float*)d_in[7];
    const float* W2     = (const float*)d_in[8];
    const float* b2     = (const float*)d_in[9];
    const float* W3     = (const float*)d_in[10];
    const float* b3     = (const float*)d_in[11];
    float* out = (float*)d_out;

    conv_w<<<768, 256, 0, stream>>>(W_ih, W_hh, b_ih, b_hh);
    conv_mlp<<<56, 256, 0, stream>>>(W1, W2, W3);
    conv_x<<<16256, 256, 0, stream>>>(padded);
    init_kernel<<<2048, 256, 0, stream>>>(hidden, out);
    step_all<<<256, 256, 0, stream>>>();
    mlp_all<<<2032, 256, 0, stream>>>(b1, b2, b3, out);
}

// Round 17
// 792.605 us; speedup vs baseline: 2.8000x; 1.0523x over previous
//
#include <hip/hip_runtime.h>
#include <math.h>
#include <stdint.h>

#define B 1024
#define H 512
#define E 256
#define L 128
#define LE (L*E)   // 32768

typedef _Float16 f16;
typedef _Float16 f16x8 __attribute__((ext_vector_type(8)));
typedef float f32x4 __attribute__((ext_vector_type(4)));
typedef const __attribute__((address_space(1))) uint32_t gu32;
typedef __attribute__((address_space(3))) uint32_t lu32;

// ---------------------------------------------------------------------------
// Persistent state in module device globals. Everything rewritten every call.
// X and H images are stored in FRAGMENT ORDER: each 64x64 image = 8 frags of
// 1 KB; frag = 16 rows x 32 k; addr = img + (rowgrp*2 + kgrp)*1024 + lane*16,
// lane = (row&15) | (kchunk<<4). A wave's MFMA A-frag load is then ONE
// coalesced 1KB global read -> A never touches LDS (round-16 restructure).
// ---------------------------------------------------------------------------
__device__ __align__(16) f16 g_Xs[128*16*4*4096];   // X images [t:128 pad][mt16][kt:4]
__device__ __align__(16) f16 g_Hh[128*16*8*4096];   // h(t) images, t=0..127 (134 MB)
__device__ __align__(16) f16 g_Ws[16*12*8192];      // gates W' [itile:16][kt:12] 128x64 (XOR layout)
__device__ __align__(16) f16 g_W1s[8*8192];         // W1' [kt:8] 128x64 (XOR layout)
__device__ __align__(16) f16 g_W2s[2*8192];         // W2' [kt:2]
__device__ __align__(16) f16 g_W3s[4*8192];         // W3' [nh:2][kt:2]
__device__ __align__(16) float g_bsum[2048];        // b_ih+b_hh, n=j*4+g order

// r15-validated sync: groups = PHYSICAL XCDs, relaxed flags, no wbl2/inv.
struct __align__(128) Flag { unsigned int v; unsigned int pad[31]; };
__device__ Flag g_flags[8][32];
__device__ unsigned int g_slot[8];

__device__ __forceinline__ float fsigm(float x) {
    return __builtin_amdgcn_rcpf(1.0f + __expf(-x));
}
__device__ __forceinline__ float ftanh(float x) {
    return 2.0f * __builtin_amdgcn_rcpf(1.0f + __expf(-2.0f * x)) - 1.0f;
}

// ---------------------------------------------------------------------------
// conv_w: gates W' fp16 tile images (gate-interleaved n=j*4+g) + bias sums
// ---------------------------------------------------------------------------
__global__ __launch_bounds__(256) void conv_w(
    const float* __restrict__ W_ih, const float* __restrict__ W_hh,
    const float* __restrict__ b_ih, const float* __restrict__ b_hh)
{
    int gid = blockIdx.x*256 + threadIdx.x;   // 196608
    int kb  = gid & 7;
    int r1  = gid >> 3;
    int row = r1 & 127;
    int r2  = r1 >> 7;
    int kt  = r2 % 12;
    int nt  = r2 / 12;
    int n = nt*128 + row;
    int g = n & 3, j = n >> 2;
    int wrow = g*512 + j;
    int k = kt*64 + kb*8;
    const float* src = (k < 256) ? (W_ih + wrow*256 + k)
                                 : (W_hh + wrow*512 + (k - 256));
    f16x8 v;
    #pragma unroll
    for (int e = 0; e < 8; ++e) v[e] = (f16)src[e];
    char* dst = (char*)g_Ws + (size_t)(nt*12 + kt)*16384
              + row*128 + ((kb*16) ^ ((row & 7) << 4));
    *(f16x8*)dst = v;
    if (gid < 2048) {
        int gg = gid & 3, jj = gid >> 2;
        g_bsum[gid] = b_ih[gg*512 + jj] + b_hh[gg*512 + jj];
    }
}

// ---------------------------------------------------------------------------
// conv_mlp: W1/W2/W3 fp16 tile images (XOR layout, unchanged)
// ---------------------------------------------------------------------------
__global__ __launch_bounds__(256) void conv_mlp(
    const float* __restrict__ W1, const float* __restrict__ W2,
    const float* __restrict__ W3)
{
    int gid = blockIdx.x*256 + threadIdx.x;   // 14336
    if (gid < 8192) {                         // W1 (128,512) -> 8 tiles
        int s = gid;
        int kb = s & 7, row = (s >> 3) & 127, kt = s >> 10;
        const float* src = W1 + row*512 + kt*64 + kb*8;
        f16x8 v;
        #pragma unroll
        for (int e = 0; e < 8; ++e) v[e] = (f16)src[e];
        char* dst = (char*)g_W1s + (size_t)kt*16384
                  + row*128 + ((kb*16) ^ ((row & 7) << 4));
        *(f16x8*)dst = v;
    } else if (gid < 10240) {                 // W2 (128,128) -> 2 tiles
        int s = gid - 8192;
        int kb = s & 7, row = (s >> 3) & 127, kt = s >> 10;
        const float* src = W2 + row*128 + kt*64 + kb*8;
        f16x8 v;
        #pragma unroll
        for (int e = 0; e < 8; ++e) v[e] = (f16)src[e];
        char* dst = (char*)g_W2s + (size_t)kt*16384
                  + row*128 + ((kb*16) ^ ((row & 7) << 4));
        *(f16x8*)dst = v;
    } else if (gid < 14336) {                 // W3 (256,128) -> [nh:2][kt:2]
        int s = gid - 10240;
        int kb = s & 7, r256 = (s >> 3) & 255, kt = s >> 11;
        int nh = r256 >> 7, row = r256 & 127;
        const float* src = W3 + r256*128 + kt*64 + kb*8;
        f16x8 v;
        #pragma unroll
        for (int e = 0; e < 8; ++e) v[e] = (f16)src[e];
        char* dst = (char*)g_W3s + (size_t)(nh*2 + kt)*16384
                  + row*128 + ((kb*16) ^ ((row & 7) << 4));
        *(f16x8*)dst = v;
    }
}

// ---------------------------------------------------------------------------
// conv_x: X fp16 images in FRAGMENT ORDER
// ---------------------------------------------------------------------------
__global__ __launch_bounds__(256) void conv_x(const float* __restrict__ padded)
{
    int gid = blockIdx.x*256 + threadIdx.x;   // 127*1024*32 = 4161536 exact
    int kq = gid & 31;            // 8-elem chunk within 256-col row
    int b  = (gid >> 5) & 1023;
    int t  = gid >> 15;
    const float* src = padded + (size_t)b*LE + t*E + kq*8;
    float4 v0 = *(const float4*)src;
    float4 v1 = *(const float4*)(src + 4);
    f16x8 v;
    v[0]=(f16)v0.x; v[1]=(f16)v0.y; v[2]=(f16)v0.z; v[3]=(f16)v0.w;
    v[4]=(f16)v1.x; v[5]=(f16)v1.y; v[6]=(f16)v1.z; v[7]=(f16)v1.w;
    int ktimg = kq >> 3;
    int kin0  = (kq & 7) * 8;                 // k-elem base within 64-k image
    int kgrp  = kin0 >> 5;
    int chunk = (kin0 & 31) >> 3;
    int row = b & 63, mt16 = b >> 6;
    int rowgrp = row >> 4;
    int lane = (row & 15) | (chunk << 4);
    char* dst = (char*)g_Xs + (size_t)((t*16 + mt16)*4 + ktimg)*8192
              + (rowgrp*2 + kgrp)*1024 + lane*16;
    *(f16x8*)dst = v;
}

// ---------------------------------------------------------------------------
// init: g_Hh[0] <- hidden (fragment order), out row 0 <- one-hot, flags reset
// ---------------------------------------------------------------------------
__global__ __launch_bounds__(256) void init_kernel(
    const float* __restrict__ hidden, float* __restrict__ out)
{
    int i = blockIdx.x * 256 + threadIdx.x;
    if (i < 256) g_flags[i >> 5][i & 31].v = 0u;
    if (i < 8) g_slot[i] = 0u;
    if (i < B*H) {
        float hv = hidden[i];
        int b = i >> 9, j = i & 511;
        int mt = b >> 6, row = b & 63, ktimg = j >> 6, kin = j & 63;
        int rowgrp = row >> 4, kgrp = kin >> 5;
        int lane = (row & 15) | (((kin & 31) >> 3) << 4);
        int elem = kin & 7;
        char* dst = (char*)g_Hh + (size_t)(mt*8 + ktimg)*8192
                  + (rowgrp*2 + kgrp)*1024 + lane*16 + elem*2;
        *(f16*)dst = (f16)hv;
    }
    if (i < B*E) {
        int b = i >> 8, e = i & 255;
        out[b*LE + e] = (e == 0) ? 1.0f : 0.0f;
    }
}

// ---------------------------------------------------------------------------
// step_all: FREE-RUNNING WAVES. 8 groups (= physical XCDs) x 32 blocks,
// 256 threads. Block owns 128 rows x 64 gate-cols. B (96 KB) persistent
// read-only LDS (staged once). A (X|H) loads are coalesced 1KB frag reads
// global->registers, 3-deep az[3][4] pipeline -> ZERO s_barriers in the kt
// loop; waves free-run. Per-wave flag-wait at kt1 (before kt4 H issue).
// Epilogue fully wave-private; one __syncthreads/step before flag release.
// ---------------------------------------------------------------------------
__global__ __launch_bounds__(256, 1) void step_all()
{
    __shared__ __align__(16) char lds[102400];   // 96K B + 4 x 1K wave Hs
    char* Bb = lds;

    const int tid  = threadIdx.x;
    const int lane = tid & 63;
    const int wv   = tid >> 6;          // 0..3
    const int l15  = lane & 15;
    const int p    = l15 & 3;
    const int klo  = (lane >> 4) << 4;
    f16* HsW = (f16*)(lds + 98304 + wv*1024);    // wave-private [32][16]

    // runtime grouping: grp = physical XCD, nt = slot within XCD.
    if (tid == 0) {
        uint32_t xcc;
        asm volatile("s_getreg_b32 %0, hwreg(HW_REG_XCC_ID)" : "=s"(xcc));
        xcc &= 7u;
        unsigned int slot = atomicAdd(&g_slot[xcc], 1u);
        ((int*)lds)[0] = (int)xcc;
        ((int*)lds)[1] = (int)(slot & 31u);
    }
    __syncthreads();
    const int grp = ((volatile int*)lds)[0];
    const int nt  = ((volatile int*)lds)[1];
    __syncthreads();   // reads done before B staging overwrites lds[0..7]

    // ---- persistent B load (once): rows (nt&1)*64..+64 of itile nt>>1 ----
    {
        const char* src = (const char*)g_Ws + (size_t)(nt >> 1)*12*16384
                        + (size_t)(nt & 1)*64*128;
        #pragma unroll
        for (int it = 0; it < 24; ++it) {
            int c = wv*24 + it;             // 0..95 chunks of 1KB
            int kt = c >> 3, cc = c & 7;
            __builtin_amdgcn_global_load_lds(
                (gu32*)(src + (size_t)kt*16384 + cc*1024 + lane*16),
                (lu32*)(Bb + c*1024 + lane*16), 16, 0, 0);
        }
    }
    float4 bs4[4];
    #pragma unroll
    for (int n = 0; n < 4; ++n)
        bs4[n] = *(const float4*)&g_bsum[nt*64 + n*16 + (l15 >> 2)*4];

    float creg[2][4];
    #pragma unroll
    for (int m = 0; m < 2; ++m)
        #pragma unroll
        for (int n = 0; n < 4; ++n) creg[m][n] = 0.0f;

    asm volatile("s_waitcnt vmcnt(0)" ::: "memory");
    __syncthreads();   // B resident for all waves

    const int sub = wv >> 1;            // which 64-row image
    const int rg2 = (wv & 1) * 2;       // rowgrp base within image

    // A frag loader: az[s] = 4 frags {m0k0, m0k1, m1k0, m1k1} = frag ids
    // rg2*2 .. rg2*2+3 of the (t,kt) image -> 4 coalesced 1KB reads.
    f16x8 az[3][4];
    auto loada = [&](int t_, int kt_, int s_) {
        const char* img = (kt_ < 4)
            ? (const char*)g_Xs + (size_t)((t_*16 + grp*2 + sub)*4 + kt_)*8192
            : (const char*)g_Hh + (size_t)((t_*16 + grp*2 + sub)*8 + (kt_-4))*8192;
        const char* fb = img + (size_t)(rg2*2)*1024 + lane*16;
        az[s_][0] = *(const f16x8*)(fb);
        az[s_][1] = *(const f16x8*)(fb + 1024);
        az[s_][2] = *(const f16x8*)(fb + 2048);
        az[s_][3] = *(const f16x8*)(fb + 3072);
    };

    // per-wave group wait: lane-parallel RELAXED polls; compiler fence exit
    auto wave_wait = [&](unsigned int target) {
        for (;;) {
            unsigned int v = __hip_atomic_load(&g_flags[grp][lane & 31].v,
                               __ATOMIC_RELAXED, __HIP_MEMORY_SCOPE_AGENT);
            if (__all(v >= target)) break;
            __builtin_amdgcn_s_sleep(1);
        }
        asm volatile("" ::: "memory");
    };

    // prologue: X(0) kt0..2
    loada(0, 0, 0); loada(0, 1, 1); loada(0, 2, 2);

    #pragma unroll 1
    for (int t = 0; t < 127; ++t) {
        f32x4 acc[2][4];
        #pragma unroll
        for (int m = 0; m < 2; ++m)
            #pragma unroll
            for (int n = 0; n < 4; ++n) acc[m][n] = (f32x4){0.f,0.f,0.f,0.f};

        #pragma unroll
        for (int kt = 0; kt < 12; ++kt) {
            const int s = kt % 3;
            const char* Br = Bb + kt*8192;
            #pragma unroll
            for (int kkl = 0; kkl < 2; ++kkl) {
                const int kb = kkl*64 + klo;
                f16x8 b[4];
                #pragma unroll
                for (int n = 0; n < 4; ++n) {
                    int r = n*16 + l15;
                    b[n] = *(const f16x8*)(Br + r*128 + (kb ^ ((r & 7) << 4)));
                }
                #pragma unroll
                for (int n = 0; n < 4; ++n) {
                    acc[0][n] = __builtin_amdgcn_mfma_f32_16x16x32_f16(
                        az[s][0 + kkl], b[n], acc[0][n], 0, 0, 0);
                    acc[1][n] = __builtin_amdgcn_mfma_f32_16x16x32_f16(
                        az[s][2 + kkl], b[n], acc[1][n], 0, 0, 0);
                }
            }
            // prefetch kt+3 into the just-consumed slot (SSA renames WAR)
            if (kt == 1) wave_wait((unsigned)t);   // h(t) visible before kt4 issue
            if (kt < 9) loada(t, kt + 3, s);
            else        loada(t + 1, kt - 9, s);   // X(t+1); g_Xs padded to t=127
        }

        // ---- wave-private epilogue: transpose -> cell -> HsW ----
        #pragma unroll
        for (int m = 0; m < 2; ++m)
            #pragma unroll
            for (int n = 0; n < 4; ++n) {
                float v0 = acc[m][n][0], v1 = acc[m][n][1];
                float v2 = acc[m][n][2], v3 = acc[m][n][3];
                float s, r;
                s = (p & 1) ? v0 : v1; r = __shfl_xor(s, 1); if (p & 1) v0 = r; else v1 = r;
                s = (p & 1) ? v2 : v3; r = __shfl_xor(s, 1); if (p & 1) v2 = r; else v3 = r;
                s = (p & 2) ? v0 : v2; r = __shfl_xor(s, 2); if (p & 2) v0 = r; else v2 = r;
                s = (p & 2) ? v1 : v3; r = __shfl_xor(s, 2); if (p & 2) v1 = r; else v3 = r;
                float iv = fsigm(v0 + bs4[n].x);
                float fv = fsigm(v1 + bs4[n].y);
                float gg = ftanh(v2 + bs4[n].z);
                float ov = fsigm(v3 + bs4[n].w);
                float cv = fv * creg[m][n] + iv * gg;
                creg[m][n] = cv;
                float hv = ov * ftanh(cv);
                int rowl = m*16 + ((lane >> 4) << 2) + p;   // 0..31 wave-local
                int coll = n*4 + (l15 >> 2);                // 0..15
                HsW[rowl*16 + coll] = (f16)hv;
            }
        asm volatile("s_waitcnt lgkmcnt(0)" ::: "memory");  // wave's Hs done
        // wave-private coalesced h store in FRAGMENT ORDER (512B runs)
        {
            int rg = lane >> 5, lo = lane & 31;
            int ktimg = nt >> 2;
            int kgrp  = (nt & 3) >> 1;
            int c0    = (nt & 1) * 2;
            char* img = (char*)g_Hh
                + (size_t)(((t + 1)*16 + grp*2 + sub)*8 + ktimg)*8192;
            int frag = (rg2 + rg)*2 + kgrp;
            f16x8 hv8 = *(const f16x8*)(HsW + (rg*16 + (lo & 15))*16 + (lo >> 4)*8);
            *(f16x8*)(img + frag*1024 + (size_t)(c0*16 + lo)*16) = hv8;
        }
        asm volatile("s_waitcnt vmcnt(0)" ::: "memory");  // h complete in L2
        __syncthreads();                                  // all waves done
        if (tid == 0)
            __hip_atomic_store(&g_flags[grp][nt].v, (unsigned)(t + 1),
                               __ATOMIC_RELAXED, __HIP_MEMORY_SCOPE_AGENT);
    }
}

// ---------------------------------------------------------------------------
// mlp_all: batched 3-layer MLP for ALL tokens. A-frag reads from the
// gH-staged buffer use the new FRAGMENT-ORDER addressing; internal Z tiles
// keep the XOR layout (self-consistent).
// ---------------------------------------------------------------------------
__global__ __launch_bounds__(256) void mlp_all(
    const float* __restrict__ b1, const float* __restrict__ b2,
    const float* __restrict__ b3, float* __restrict__ out)
{
    __shared__ char lds[65536];
    char* Wb = lds;            // 2 x 16384
    char* Ab = lds + 32768;    // 2 x 8192 (later Z2)
    char* Z1 = lds + 49152;    // 16384
    const int tid  = threadIdx.x;
    const int lane = tid & 63;
    const int w    = tid >> 6;
    const int bi   = blockIdx.x;
    const int tok  = 1 + (bi >> 4);
    const int mt   = bi & 15;
    const char* gH = (const char*)g_Hh + (size_t)(tok*16 + mt)*8*8192;
    float* outb = out + (size_t)(mt*64)*LE + (size_t)tok*E;

    float b1v[2], b2v[2], b3v[2][2];
    #pragma unroll
    for (int n = 0; n < 2; ++n) {
        int col = w*32 + n*16 + (lane & 15);
        b1v[n] = b1[col]; b2v[n] = b2[col];
        b3v[0][n] = b3[col]; b3v[1][n] = b3[128 + col];
    }
    const int kb0_0 = ((lane >> 4) << 4);

    f32x4 acc[4][2];
    #pragma unroll
    for (int m = 0; m < 4; ++m) { acc[m][0] = (f32x4){0,0,0,0}; acc[m][1] = (f32x4){0,0,0,0}; }

    #pragma unroll
    for (int it = 0; it < 2; ++it) {
        int c = w*2 + it;
        __builtin_amdgcn_global_load_lds((gu32*)(gH + c*1024 + lane*16),
                                         (lu32*)(Ab + c*1024 + lane*16), 16, 0, 0);
    }
    #pragma unroll
    for (int it = 0; it < 4; ++it) {
        int c = w*4 + it;
        __builtin_amdgcn_global_load_lds((gu32*)((const char*)g_W1s + c*1024 + lane*16),
                                         (lu32*)(Wb + c*1024 + lane*16), 16, 0, 0);
    }
    __syncthreads();

    for (int kt = 0; kt < 8; ++kt) {
        const int cur = kt & 1;
        if (kt < 7) {
            const char* gA = gH + (size_t)(kt+1)*8192;
            const char* gW = (const char*)g_W1s + (size_t)(kt+1)*16384;
            char* dA = Ab + (cur^1)*8192;
            char* dW = Wb + (cur^1)*16384;
            #pragma unroll
            for (int it = 0; it < 2; ++it) {
                int c = w*2 + it;
                __builtin_amdgcn_global_load_lds((gu32*)(gA + c*1024 + lane*16),
                                                 (lu32*)(dA + c*1024 + lane*16), 16, 0, 0);
            }
            #pragma unroll
            for (int it = 0; it < 4; ++it) {
                int c = w*4 + it;
                __builtin_amdgcn_global_load_lds((gu32*)(gW + c*1024 + lane*16),
                                                 (lu32*)(dW + c*1024 + lane*16), 16, 0, 0);
            }
        }
        const char* Ar = Ab + cur*8192;
        const char* Br = Wb + cur*16384;
        #pragma unroll
        for (int kk = 0; kk < 2; ++kk) {
            const int kb0 = kk*64 + kb0_0;
            f16x8 a[4], b[2];
            #pragma unroll
            for (int m = 0; m < 4; ++m)
                a[m] = *(const f16x8*)(Ar + (size_t)(m*2 + kk)*1024 + lane*16);
            #pragma unroll
            for (int n = 0; n < 2; ++n) {
                int br = w*32 + n*16 + (lane & 15);
                b[n] = *(const f16x8*)(Br + br*128 + (kb0 ^ ((br & 7) << 4)));
            }
            #pragma unroll
            for (int m = 0; m < 4; ++m)
                #pragma unroll
                for (int n = 0; n < 2; ++n)
                    acc[m][n] = __builtin_amdgcn_mfma_f32_16x16x32_f16(a[m], b[n], acc[m][n], 0, 0, 0);
        }
        __syncthreads();
    }

    #pragma unroll
    for (int m = 0; m < 4; ++m)
        #pragma unroll
        for (int n = 0; n < 2; ++n)
            #pragma unroll
            for (int i = 0; i < 4; ++i) {
                int row = m*16 + ((lane >> 4) << 2) + i;
                int col = w*32 + n*16 + (lane & 15);
                float v = fmaxf(acc[m][n][i] + b1v[n], 0.0f);
                *(f16*)(Z1 + (col >> 6)*8192 + row*128
                        + (((col & 63)*2) ^ ((row & 7) << 4))) = (f16)v;
            }
    __syncthreads();

    #pragma unroll
    for (int it = 0; it < 8; ++it) {
        int c = w*8 + it;
        __builtin_amdgcn_global_load_lds((gu32*)((const char*)g_W2s + c*1024 + lane*16),
                                         (lu32*)(Wb + c*1024 + lane*16), 16, 0, 0);
    }
    __syncthreads();
    #pragma unroll
    for (int m = 0; m < 4; ++m) { acc[m][0] = (f32x4){0,0,0,0}; acc[m][1] = (f32x4){0,0,0,0}; }
    #pragma unroll
    for (int kt = 0; kt < 2; ++kt)
        #pragma unroll
        for (int kk = 0; kk < 2; ++kk) {
            const int kb0 = kk*64 + kb0_0;
            f16x8 a[4], b[2];
            #pragma unroll
            for (int m = 0; m < 4; ++m) {
                int ar = m*16 + (lane & 15);
                a[m] = *(const f16x8*)(Z1 + kt*8192 + ar*128 + (kb0 ^ ((ar & 7) << 4)));
            }
            #pragma unroll
            for (int n = 0; n < 2; ++n) {
                int br = w*32 + n*16 + (lane & 15);
                b[n] = *(const f16x8*)(Wb + kt*16384 + br*128 + (kb0 ^ ((br & 7) << 4)));
            }
            #pragma unroll
            for (int m = 0; m < 4; ++m)
                #pragma unroll
                for (int n = 0; n < 2; ++n)
                    acc[m][n] = __builtin_amdgcn_mfma_f32_16x16x32_f16(a[m], b[n], acc[m][n], 0, 0, 0);
        }
    __syncthreads();

    #pragma unroll
    for (int m = 0; m < 4; ++m)
        #pragma unroll
        for (int n = 0; n < 2; ++n)
            #pragma unroll
            for (int i = 0; i < 4; ++i) {
                int row = m*16 + ((lane >> 4) << 2) + i;
                int col = w*32 + n*16 + (lane & 15);
                float v = fmaxf(acc[m][n][i] + b2v[n], 0.0f);
                *(f16*)(Ab + (col >> 6)*8192 + row*128
                        + (((col & 63)*2) ^ ((row & 7) << 4))) = (f16)v;
            }
    __syncthreads();

    #pragma unroll
    for (int nh = 0; nh < 2; ++nh) {
        #pragma unroll
        for (int it = 0; it < 8; ++it) {
            int c = w*8 + it;
            __builtin_amdgcn_global_load_lds(
                (gu32*)((const char*)g_W3s + (size_t)nh*32768 + c*1024 + lane*16),
                (lu32*)(Wb + c*1024 + lane*16), 16, 0, 0);
        }
        __syncthreads();
        #pragma unroll
        for (int m = 0; m < 4; ++m) { acc[m][0] = (f32x4){0,0,0,0}; acc[m][1] = (f32x4){0,0,0,0}; }
        #pragma unroll
        for (int kt = 0; kt < 2; ++kt)
            #pragma unroll
            for (int kk = 0; kk < 2; ++kk) {
                const int kb0 = kk*64 + kb0_0;
                f16x8 a[4], b[2];
                #pragma unroll
                for (int m = 0; m < 4; ++m) {
                    int ar = m*16 + (lane & 15);
                    a[m] = *(const f16x8*)(Ab + kt*8192 + ar*128 + (kb0 ^ ((ar & 7) << 4)));
                }
                #pragma unroll
                for (int n = 0; n < 2; ++n) {
                    int br = w*32 + n*16 + (lane & 15);
                    b[n] = *(const f16x8*)(Wb + kt*16384 + br*128 + (kb0 ^ ((br & 7) << 4)));
                }
                #pragma unroll
                for (int m = 0; m < 4; ++m)
                    #pragma unroll
                    for (int n = 0; n < 2; ++n)
                        acc[m][n] = __builtin_amdgcn_mfma_f32_16x16x32_f16(a[m], b[n], acc[m][n], 0, 0, 0);
            }
        #pragma unroll
        for (int m = 0; m < 4; ++m)
            #pragma unroll
            for (int n = 0; n < 2; ++n)
                #pragma unroll
                for (int i = 0; i < 4; ++i) {
                    int row = m*16 + ((lane >> 4) << 2) + i;
                    int col = nh*128 + w*32 + n*16 + (lane & 15);
                    outb[(size_t)row*LE + col] = acc[m][n][i] + b3v[nh][n];
                }
        __syncthreads();
    }
}

// ---------------------------------------------------------------------------
extern "C" void kernel_launch(void* const* d_in, const int* in_sizes, int n_in,
                              void* d_out, int out_size, void* d_ws, size_t ws_size,
                              hipStream_t stream) {
    (void)in_sizes; (void)n_in; (void)out_size; (void)d_ws; (void)ws_size;
    const float* hidden = (const float*)d_in[0];
    const float* padded = (const float*)d_in[1];
    const float* W_ih   = (const float*)d_in[2];
    const float* W_hh   = (const float*)d_in[3];
    const float* b_ih   = (const float*)d_in[4];
    const float* b_hh   = (const float*)d_in[5];
    const float* W1     = (const float*)d_in[6];
    const float* b1     = (const float*)d_in[7];
    const float* W2     = (const float*)d_in[8];
    const float* b2     = (const float*)d_in[9];
    const float* W3     = (const float*)d_in[10];
    const float* b3     = (const float*)d_in[11];
    float* out = (float*)d_out;

    conv_w<<<768, 256, 0, stream>>>(W_ih, W_hh, b_ih, b_hh);
    conv_mlp<<<56, 256, 0, stream>>>(W1, W2, W3);
    conv_x<<<16256, 256, 0, stream>>>(padded);
    init_kernel<<<2048, 256, 0, stream>>>(hidden, out);
    step_all<<<256, 256, 0, stream>>>();
    mlp_all<<<2032, 256, 0, stream>>>(b1, b2, b3, out);
}

// Round 18
// 690.241 us; speedup vs baseline: 3.2152x; 1.1483x over previous
//
#include <hip/hip_runtime.h>
#include <math.h>
#include <stdint.h>

#define B 1024
#define H 512
#define E 256
#define L 128
#define LE (L*E)   // 32768

typedef _Float16 f16;
typedef _Float16 f16x8 __attribute__((ext_vector_type(8)));
typedef float f32x4 __attribute__((ext_vector_type(4)));
typedef const __attribute__((address_space(1))) uint32_t gu32;
typedef __attribute__((address_space(3))) uint32_t lu32;

// ---------------------------------------------------------------------------
// Persistent state in module device globals. Everything rewritten every call.
// X/H images in FRAGMENT ORDER (r17): 64x64 image = 8 frags of 1 KB;
// frag = 16 rows x 32 k; addr = img + frag*1024 + lane*16.
// W' images: XOR layout, rows GATE-PLANAR per 64-col block (r18): block col
// c = g*16 + jl -> wrow = g*512 + ntblock*16 + jl, so a cell's 4 gates land
// in the 4 n-frags of ONE lane (no epilogue shuffle transpose).
// ---------------------------------------------------------------------------
__device__ __align__(16) f16 g_Xs[128*16*4*4096];   // X images [t:128 pad][mt16][kt:4]
__device__ __align__(16) f16 g_Hh[128*16*8*4096];   // h(t) images, t=0..127 (134 MB)
__device__ __align__(16) f16 g_Ws[16*12*8192];      // gates W' [itile:16][kt:12] 128x64
__device__ __align__(16) f16 g_W1s[8*8192];         // W1' [kt:8] 128x64 (XOR layout)
__device__ __align__(16) f16 g_W2s[2*8192];         // W2' [kt:2]
__device__ __align__(16) f16 g_W3s[4*8192];         // W3' [nh:2][kt:2]
__device__ __align__(16) float g_bsum[2048];        // b_ih+b_hh, NATURAL order g*512+j

// r15-validated sync: groups = PHYSICAL XCDs, relaxed flags, no wbl2/inv.
struct __align__(128) Flag { unsigned int v; unsigned int pad[31]; };
__device__ Flag g_flags[8][32];
__device__ unsigned int g_slot[8];

__device__ __forceinline__ float fsigm(float x) {
    return __builtin_amdgcn_rcpf(1.0f + __expf(-x));
}
__device__ __forceinline__ float ftanh(float x) {
    return 2.0f * __builtin_amdgcn_rcpf(1.0f + __expf(-2.0f * x)) - 1.0f;
}

// ---------------------------------------------------------------------------
// conv_w: gates W' images, GATE-PLANAR rows (r18) + bias sums natural order
// ---------------------------------------------------------------------------
__global__ __launch_bounds__(256) void conv_w(
    const float* __restrict__ W_ih, const float* __restrict__ W_hh,
    const float* __restrict__ b_ih, const float* __restrict__ b_hh)
{
    int gid = blockIdx.x*256 + threadIdx.x;   // 196608
    int kb  = gid & 7;
    int r1  = gid >> 3;
    int row = r1 & 127;
    int r2  = r1 >> 7;
    int kt  = r2 % 12;
    int nt  = r2 / 12;
    // gate-planar: block (ntblock = nt*2 + row>>6) col c = row&63 = g*16+jl
    int ntblock = nt*2 + (row >> 6);
    int c = row & 63;
    int wrow = (c >> 4)*512 + ntblock*16 + (c & 15);
    int k = kt*64 + kb*8;
    const float* src = (k < 256) ? (W_ih + wrow*256 + k)
                                 : (W_hh + wrow*512 + (k - 256));
    f16x8 v;
    #pragma unroll
    for (int e = 0; e < 8; ++e) v[e] = (f16)src[e];
    char* dst = (char*)g_Ws + (size_t)(nt*12 + kt)*16384
              + row*128 + ((kb*16) ^ ((row & 7) << 4));
    *(f16x8*)dst = v;
    if (gid < 2048) g_bsum[gid] = b_ih[gid] + b_hh[gid];
}

// ---------------------------------------------------------------------------
// conv_mlp: W1/W2/W3 fp16 tile images (XOR layout, unchanged)
// ---------------------------------------------------------------------------
__global__ __launch_bounds__(256) void conv_mlp(
    const float* __restrict__ W1, const float* __restrict__ W2,
    const float* __restrict__ W3)
{
    int gid = blockIdx.x*256 + threadIdx.x;   // 14336
    if (gid < 8192) {                         // W1 (128,512) -> 8 tiles
        int s = gid;
        int kb = s & 7, row = (s >> 3) & 127, kt = s >> 10;
        const float* src = W1 + row*512 + kt*64 + kb*8;
        f16x8 v;
        #pragma unroll
        for (int e = 0; e < 8; ++e) v[e] = (f16)src[e];
        char* dst = (char*)g_W1s + (size_t)kt*16384
                  + row*128 + ((kb*16) ^ ((row & 7) << 4));
        *(f16x8*)dst = v;
    } else if (gid < 10240) {                 // W2 (128,128) -> 2 tiles
        int s = gid - 8192;
        int kb = s & 7, row = (s >> 3) & 127, kt = s >> 10;
        const float* src = W2 + row*128 + kt*64 + kb*8;
        f16x8 v;
        #pragma unroll
        for (int e = 0; e < 8; ++e) v[e] = (f16)src[e];
        char* dst = (char*)g_W2s + (size_t)kt*16384
                  + row*128 + ((kb*16) ^ ((row & 7) << 4));
        *(f16x8*)dst = v;
    } else if (gid < 14336) {                 // W3 (256,128) -> [nh:2][kt:2]
        int s = gid - 10240;
        int kb = s & 7, r256 = (s >> 3) & 255, kt = s >> 11;
        int nh = r256 >> 7, row = r256 & 127;
        const float* src = W3 + r256*128 + kt*64 + kb*8;
        f16x8 v;
        #pragma unroll
        for (int e = 0; e < 8; ++e) v[e] = (f16)src[e];
        char* dst = (char*)g_W3s + (size_t)(nh*2 + kt)*16384
                  + row*128 + ((kb*16) ^ ((row & 7) << 4));
        *(f16x8*)dst = v;
    }
}

// ---------------------------------------------------------------------------
// conv_x: X fp16 images in FRAGMENT ORDER (unchanged from r17)
// ---------------------------------------------------------------------------
__global__ __launch_bounds__(256) void conv_x(const float* __restrict__ padded)
{
    int gid = blockIdx.x*256 + threadIdx.x;   // 127*1024*32 = 4161536 exact
    int kq = gid & 31;
    int b  = (gid >> 5) & 1023;
    int t  = gid >> 15;
    const float* src = padded + (size_t)b*LE + t*E + kq*8;
    float4 v0 = *(const float4*)src;
    float4 v1 = *(const float4*)(src + 4);
    f16x8 v;
    v[0]=(f16)v0.x; v[1]=(f16)v0.y; v[2]=(f16)v0.z; v[3]=(f16)v0.w;
    v[4]=(f16)v1.x; v[5]=(f16)v1.y; v[6]=(f16)v1.z; v[7]=(f16)v1.w;
    int ktimg = kq >> 3;
    int kin0  = (kq & 7) * 8;
    int kgrp  = kin0 >> 5;
    int chunk = (kin0 & 31) >> 3;
    int row = b & 63, mt16 = b >> 6;
    int rowgrp = row >> 4;
    int lane = (row & 15) | (chunk << 4);
    char* dst = (char*)g_Xs + (size_t)((t*16 + mt16)*4 + ktimg)*8192
              + (rowgrp*2 + kgrp)*1024 + lane*16;
    *(f16x8*)dst = v;
}

// ---------------------------------------------------------------------------
// init: g_Hh[0] <- hidden (fragment order), out row 0 <- one-hot, flags reset
// ---------------------------------------------------------------------------
__global__ __launch_bounds__(256) void init_kernel(
    const float* __restrict__ hidden, float* __restrict__ out)
{
    int i = blockIdx.x * 256 + threadIdx.x;
    if (i < 256) g_flags[i >> 5][i & 31].v = 0u;
    if (i < 8) g_slot[i] = 0u;
    if (i < B*H) {
        float hv = hidden[i];
        int b = i >> 9, j = i & 511;
        int mt = b >> 6, row = b & 63, ktimg = j >> 6, kin = j & 63;
        int rowgrp = row >> 4, kgrp = kin >> 5;
        int lane = (row & 15) | (((kin & 31) >> 3) << 4);
        int elem = kin & 7;
        char* dst = (char*)g_Hh + (size_t)(mt*8 + ktimg)*8192
                  + (rowgrp*2 + kgrp)*1024 + lane*16 + elem*2;
        *(f16*)dst = (f16)hv;
    }
    if (i < B*E) {
        int b = i >> 8, e = i & 255;
        out[b*LE + e] = (e == 0) ? 1.0f : 0.0f;
    }
}

// ---------------------------------------------------------------------------
// step_all: r17 free-running structure + r18 shuffle-free epilogue.
// 8 groups (= physical XCDs) x 32 blocks, 256 threads. B (96 KB) persistent
// read-only LDS; A frags coalesced global->reg (az[3][4] pipeline); zero
// s_barriers in the kt loop. Gate-planar B layout -> acc[m][g][i] holds all
// 4 gates of cell (row m*16+quad*4+i, col nt*16+l15) IN-LANE: epilogue is
// pure VALU, no ds_swizzle.
// ---------------------------------------------------------------------------
__global__ __launch_bounds__(256, 1) void step_all()
{
    __shared__ __align__(16) char lds[102400];   // 96K B + 4 x 1K wave Hs
    char* Bb = lds;

    const int tid  = threadIdx.x;
    const int lane = tid & 63;
    const int wv   = tid >> 6;          // 0..3
    const int l15  = lane & 15;
    const int quad = lane >> 4;
    const int klo  = quad << 4;
    f16* HsW = (f16*)(lds + 98304 + wv*1024);    // wave-private [32][16]

    // runtime grouping: grp = physical XCD, nt = slot within XCD.
    if (tid == 0) {
        uint32_t xcc;
        asm volatile("s_getreg_b32 %0, hwreg(HW_REG_XCC_ID)" : "=s"(xcc));
        xcc &= 7u;
        unsigned int slot = atomicAdd(&g_slot[xcc], 1u);
        ((int*)lds)[0] = (int)xcc;
        ((int*)lds)[1] = (int)(slot & 31u);
    }
    __syncthreads();
    const int grp = ((volatile int*)lds)[0];
    const int nt  = ((volatile int*)lds)[1];
    __syncthreads();   // reads done before B staging overwrites lds[0..7]

    // ---- persistent B load (once): rows (nt&1)*64..+64 of itile nt>>1 ----
    {
        const char* src = (const char*)g_Ws + (size_t)(nt >> 1)*12*16384
                        + (size_t)(nt & 1)*64*128;
        #pragma unroll
        for (int it = 0; it < 24; ++it) {
            int c = wv*24 + it;             // 0..95 chunks of 1KB
            int kt = c >> 3, cc = c & 7;
            __builtin_amdgcn_global_load_lds(
                (gu32*)(src + (size_t)kt*16384 + cc*1024 + lane*16),
                (lu32*)(Bb + c*1024 + lane*16), 16, 0, 0);
        }
    }
    // per-lane bias: gate g at col j = nt*16 + l15
    float bsv[4];
    #pragma unroll
    for (int g = 0; g < 4; ++g) bsv[g] = g_bsum[g*512 + nt*16 + l15];

    float creg[2][4];
    #pragma unroll
    for (int m = 0; m < 2; ++m)
        #pragma unroll
        for (int i = 0; i < 4; ++i) creg[m][i] = 0.0f;

    asm volatile("s_waitcnt vmcnt(0)" ::: "memory");
    __syncthreads();   // B resident for all waves

    const int sub = wv >> 1;            // which 64-row image
    const int rg2 = (wv & 1) * 2;       // rowgrp base within image

    f16x8 az[3][4];
    auto loada = [&](int t_, int kt_, int s_) {
        const char* img = (kt_ < 4)
            ? (const char*)g_Xs + (size_t)((t_*16 + grp*2 + sub)*4 + kt_)*8192
            : (const char*)g_Hh + (size_t)((t_*16 + grp*2 + sub)*8 + (kt_-4))*8192;
        const char* fb = img + (size_t)(rg2*2)*1024 + lane*16;
        az[s_][0] = *(const f16x8*)(fb);
        az[s_][1] = *(const f16x8*)(fb + 1024);
        az[s_][2] = *(const f16x8*)(fb + 2048);
        az[s_][3] = *(const f16x8*)(fb + 3072);
    };

    auto wave_wait = [&](unsigned int target) {
        for (;;) {
            unsigned int v = __hip_atomic_load(&g_flags[grp][lane & 31].v,
                               __ATOMIC_RELAXED, __HIP_MEMORY_SCOPE_AGENT);
            if (__all(v >= target)) break;
            __builtin_amdgcn_s_sleep(1);
        }
        asm volatile("" ::: "memory");
    };

    // prologue: X(0) kt0..2
    loada(0, 0, 0); loada(0, 1, 1); loada(0, 2, 2);

    #pragma unroll 1
    for (int t = 0; t < 127; ++t) {
        f32x4 acc[2][4];
        #pragma unroll
        for (int m = 0; m < 2; ++m)
            #pragma unroll
            for (int n = 0; n < 4; ++n) acc[m][n] = (f32x4){0.f,0.f,0.f,0.f};

        #pragma unroll
        for (int kt = 0; kt < 12; ++kt) {
            const int s = kt % 3;
            const char* Br = Bb + kt*8192;
            #pragma unroll
            for (int kkl = 0; kkl < 2; ++kkl) {
                const int kb = kkl*64 + klo;
                f16x8 b[4];
                #pragma unroll
                for (int n = 0; n < 4; ++n) {
                    int r = n*16 + l15;
                    b[n] = *(const f16x8*)(Br + r*128 + (kb ^ ((r & 7) << 4)));
                }
                #pragma unroll
                for (int n = 0; n < 4; ++n) {
                    acc[0][n] = __builtin_amdgcn_mfma_f32_16x16x32_f16(
                        az[s][0 + kkl], b[n], acc[0][n], 0, 0, 0);
                    acc[1][n] = __builtin_amdgcn_mfma_f32_16x16x32_f16(
                        az[s][2 + kkl], b[n], acc[1][n], 0, 0, 0);
                }
            }
            if (kt == 1) wave_wait((unsigned)t);   // h(t) visible before kt4 issue
            if (kt < 9) loada(t, kt + 3, s);
            else        loada(t + 1, kt - 9, s);   // X(t+1); g_Xs padded
        }

        // ---- shuffle-free epilogue: all 4 gates in-lane per cell ----
        #pragma unroll
        for (int m = 0; m < 2; ++m)
            #pragma unroll
            for (int i = 0; i < 4; ++i) {
                float iv = fsigm(acc[m][0][i] + bsv[0]);
                float fv = fsigm(acc[m][1][i] + bsv[1]);
                float gg = ftanh(acc[m][2][i] + bsv[2]);
                float ov = fsigm(acc[m][3][i] + bsv[3]);
                float cv = fv * creg[m][i] + iv * gg;
                creg[m][i] = cv;
                float hv = ov * ftanh(cv);
                int rowl = m*16 + quad*4 + i;       // 0..31 wave-local
                HsW[rowl*16 + l15] = (f16)hv;       // col = l15
            }
        asm volatile("s_waitcnt lgkmcnt(0)" ::: "memory");  // wave's Hs done
        // wave-private coalesced h store in FRAGMENT ORDER (unchanged r17)
        {
            int rg = lane >> 5, lo = lane & 31;
            int ktimg = nt >> 2;
            int kgrp  = (nt & 3) >> 1;
            int c0    = (nt & 1) * 2;
            char* img = (char*)g_Hh
                + (size_t)(((t + 1)*16 + grp*2 + sub)*8 + ktimg)*8192;
            int frag = (rg2 + rg)*2 + kgrp;
            f16x8 hv8 = *(const f16x8*)(HsW + (rg*16 + (lo & 15))*16 + (lo >> 4)*8);
            *(f16x8*)(img + frag*1024 + (size_t)(c0*16 + lo)*16) = hv8;
        }
        asm volatile("s_waitcnt vmcnt(0)" ::: "memory");  // h complete in L2
        __syncthreads();                                  // all waves done
        if (tid == 0)
            __hip_atomic_store(&g_flags[grp][nt].v, (unsigned)(t + 1),
                               __ATOMIC_RELAXED, __HIP_MEMORY_SCOPE_AGENT);
    }
}

// ---------------------------------------------------------------------------
// mlp_all: batched 3-layer MLP for ALL tokens (r17 structure, unchanged)
// ---------------------------------------------------------------------------
__global__ __launch_bounds__(256) void mlp_all(
    const float* __restrict__ b1, const float* __restrict__ b2,
    const float* __restrict__ b3, float* __restrict__ out)
{
    __shared__ char lds[65536];
    char* Wb = lds;            // 2 x 16384
    char* Ab = lds + 32768;    // 2 x 8192 (later Z2)
    char* Z1 = lds + 49152;    // 16384
    const int tid  = threadIdx.x;
    const int lane = tid & 63;
    const int w    = tid >> 6;
    const int bi   = blockIdx.x;
    const int tok  = 1 + (bi >> 4);
    const int mt   = bi & 15;
    const char* gH = (const char*)g_Hh + (size_t)(tok*16 + mt)*8*8192;
    float* outb = out + (size_t)(mt*64)*LE + (size_t)tok*E;

    float b1v[2], b2v[2], b3v[2][2];
    #pragma unroll
    for (int n = 0; n < 2; ++n) {
        int col = w*32 + n*16 + (lane & 15);
        b1v[n] = b1[col]; b2v[n] = b2[col];
        b3v[0][n] = b3[col]; b3v[1][n] = b3[128 + col];
    }
    const int kb0_0 = ((lane >> 4) << 4);

    f32x4 acc[4][2];
    #pragma unroll
    for (int m = 0; m < 4; ++m) { acc[m][0] = (f32x4){0,0,0,0}; acc[m][1] = (f32x4){0,0,0,0}; }

    #pragma unroll
    for (int it = 0; it < 2; ++it) {
        int c = w*2 + it;
        __builtin_amdgcn_global_load_lds((gu32*)(gH + c*1024 + lane*16),
                                         (lu32*)(Ab + c*1024 + lane*16), 16, 0, 0);
    }
    #pragma unroll
    for (int it = 0; it < 4; ++it) {
        int c = w*4 + it;
        __builtin_amdgcn_global_load_lds((gu32*)((const char*)g_W1s + c*1024 + lane*16),
                                         (lu32*)(Wb + c*1024 + lane*16), 16, 0, 0);
    }
    __syncthreads();

    for (int kt = 0; kt < 8; ++kt) {
        const int cur = kt & 1;
        if (kt < 7) {
            const char* gA = gH + (size_t)(kt+1)*8192;
            const char* gW = (const char*)g_W1s + (size_t)(kt+1)*16384;
            char* dA = Ab + (cur^1)*8192;
            char* dW = Wb + (cur^1)*16384;
            #pragma unroll
            for (int it = 0; it < 2; ++it) {
                int c = w*2 + it;
                __builtin_amdgcn_global_load_lds((gu32*)(gA + c*1024 + lane*16),
                                                 (lu32*)(dA + c*1024 + lane*16), 16, 0, 0);
            }
            #pragma unroll
            for (int it = 0; it < 4; ++it) {
                int c = w*4 + it;
                __builtin_amdgcn_global_load_lds((gu32*)(gW + c*1024 + lane*16),
                                                 (lu32*)(dW + c*1024 + lane*16), 16, 0, 0);
            }
        }
        const char* Ar = Ab + cur*8192;
        const char* Br = Wb + cur*16384;
        #pragma unroll
        for (int kk = 0; kk < 2; ++kk) {
            const int kb0 = kk*64 + kb0_0;
            f16x8 a[4], b[2];
            #pragma unroll
            for (int m = 0; m < 4; ++m)
                a[m] = *(const f16x8*)(Ar + (size_t)(m*2 + kk)*1024 + lane*16);
            #pragma unroll
            for (int n = 0; n < 2; ++n) {
                int br = w*32 + n*16 + (lane & 15);
                b[n] = *(const f16x8*)(Br + br*128 + (kb0 ^ ((br & 7) << 4)));
            }
            #pragma unroll
            for (int m = 0; m < 4; ++m)
                #pragma unroll
                for (int n = 0; n < 2; ++n)
                    acc[m][n] = __builtin_amdgcn_mfma_f32_16x16x32_f16(a[m], b[n], acc[m][n], 0, 0, 0);
        }
        __syncthreads();
    }

    #pragma unroll
    for (int m = 0; m < 4; ++m)
        #pragma unroll
        for (int n = 0; n < 2; ++n)
            #pragma unroll
            for (int i = 0; i < 4; ++i) {
                int row = m*16 + ((lane >> 4) << 2) + i;
                int col = w*32 + n*16 + (lane & 15);
                float v = fmaxf(acc[m][n][i] + b1v[n], 0.0f);
                *(f16*)(Z1 + (col >> 6)*8192 + row*128
                        + (((col & 63)*2) ^ ((row & 7) << 4))) = (f16)v;
            }
    __syncthreads();

    #pragma unroll
    for (int it = 0; it < 8; ++it) {
        int c = w*8 + it;
        __builtin_amdgcn_global_load_lds((gu32*)((const char*)g_W2s + c*1024 + lane*16),
                                         (lu32*)(Wb + c*1024 + lane*16), 16, 0, 0);
    }
    __syncthreads();
    #pragma unroll
    for (int m = 0; m < 4; ++m) { acc[m][0] = (f32x4){0,0,0,0}; acc[m][1] = (f32x4){0,0,0,0}; }
    #pragma unroll
    for (int kt = 0; kt < 2; ++kt)
        #pragma unroll
        for (int kk = 0; kk < 2; ++kk) {
            const int kb0 = kk*64 + kb0_0;
            f16x8 a[4], b[2];
            #pragma unroll
            for (int m = 0; m < 4; ++m) {
                int ar = m*16 + (lane & 15);
                a[m] = *(const f16x8*)(Z1 + kt*8192 + ar*128 + (kb0 ^ ((ar & 7) << 4)));
            }
            #pragma unroll
            for (int n = 0; n < 2; ++n) {
                int br = w*32 + n*16 + (lane & 15);
                b[n] = *(const f16x8*)(Wb + kt*16384 + br*128 + (kb0 ^ ((br & 7) << 4)));
            }
            #pragma unroll
            for (int m = 0; m < 4; ++m)
                #pragma unroll
                for (int n = 0; n < 2; ++n)
                    acc[m][n] = __builtin_amdgcn_mfma_f32_16x16x32_f16(a[m], b[n], acc[m][n], 0, 0, 0);
        }
    __syncthreads();

    #pragma unroll
    for (int m = 0; m < 4; ++m)
        #pragma unroll
        for (int n = 0; n < 2; ++n)
            #pragma unroll
            for (int i = 0; i < 4; ++i) {
                int row = m*16 + ((lane >> 4) << 2) + i;
                int col = w*32 + n*16 + (lane & 15);
                float v = fmaxf(acc[m][n][i] + b2v[n], 0.0f);
                *(f16*)(Ab + (col >> 6)*8192 + row*128
                        + (((col & 63)*2) ^ ((row & 7) << 4))) = (f16)v;
            }
    __syncthreads();

    #pragma unroll
    for (int nh = 0; nh < 2; ++nh) {
        #pragma unroll
        for (int it = 0; it < 8; ++it) {
            int c = w*8 + it;
            __builtin_amdgcn_global_load_lds(
                (gu32*)((const char*)g_W3s + (size_t)nh*32768 + c*1024 + lane*16),
                (lu32*)(Wb + c*1024 + lane*16), 16, 0, 0);
        }
        __syncthreads();
        #pragma unroll
        for (int m = 0; m < 4; ++m) { acc[m][0] = (f32x4){0,0,0,0}; acc[m][1] = (f32x4){0,0,0,0}; }
        #pragma unroll
        for (int kt = 0; kt < 2; ++kt)
            #pragma unroll
            for (int kk = 0; kk < 2; ++kk) {
                const int kb0 = kk*64 + kb0_0;
                f16x8 a[4], b[2];
                #pragma unroll
                for (int m = 0; m < 4; ++m) {
                    int ar = m*16 + (lane & 15);
                    a[m] = *(const f16x8*)(Ab + kt*8192 + ar*128 + (kb0 ^ ((ar & 7) << 4)));
                }
                #pragma unroll
                for (int n = 0; n < 2; ++n) {
                    int br = w*32 + n*16 + (lane & 15);
                    b[n] = *(const f16x8*)(Wb + kt*16384 + br*128 + (kb0 ^ ((br & 7) << 4)));
                }
                #pragma unroll
                for (int m = 0; m < 4; ++m)
                    #pragma unroll
                    for (int n = 0; n < 2; ++n)
                        acc[m][n] = __builtin_amdgcn_mfma_f32_16x16x32_f16(a[m], b[n], acc[m][n], 0, 0, 0);
            }
        #pragma unroll
        for (int m = 0; m < 4; ++m)
            #pragma unroll
            for (int n = 0; n < 2; ++n)
                #pragma unroll
                for (int i = 0; i < 4; ++i) {
                    int row = m*16 + ((lane >> 4) << 2) + i;
                    int col = nh*128 + w*32 + n*16 + (lane & 15);
                    outb[(size_t)row*LE + col] = acc[m][n][i] + b3v[nh][n];
                }
        __syncthreads();
    }
}

// ---------------------------------------------------------------------------
extern "C" void kernel_launch(void* const* d_in, const int* in_sizes, int n_in,
                              void* d_out, int out_size, void* d_ws, size_t ws_size,
                              hipStream_t stream) {
    (void)in_sizes; (void)n_in; (void)out_size; (void)d_ws; (void)ws_size;
    const float* hidden = (const float*)d_in[0];
    const float* padded = (const float*)d_in[1];
    const float* W_ih   = (const float*)d_in[2];
    const float* W_hh   = (const float*)d_in[3];
    const float* b_ih   = (const float*)d_in[4];
    const float* b_hh   = (const float*)d_in[5];
    const float* W1     = (const float*)d_in[6];
    const float* b1     = (const float*)d_in[7];
    const float* W2     = (const float*)d_in[8];
    const float* b2     = (const float*)d_in[9];
    const float* W3     = (const float*)d_in[10];
    const float* b3     = (const float*)d_in[11];
    float* out = (float*)d_out;

    conv_w<<<768, 256, 0, stream>>>(W_ih, W_hh, b_ih, b_hh);
    conv_mlp<<<56, 256, 0, stream>>>(W1, W2, W3);
    conv_x<<<16256, 256, 0, stream>>>(padded);
    init_kernel<<<2048, 256, 0, stream>>>(hidden, out);
    step_all<<<256, 256, 0, stream>>>();
    mlp_all<<<2032, 256, 0, stream>>>(b1, b2, b3, out);
}

// Round 19
// 655.058 us; speedup vs baseline: 3.3879x; 1.0537x over previous
//
#include <hip/hip_runtime.h>
#include <math.h>
#include <stdint.h>

#define B 1024
#define H 512
#define E 256
#define L 128
#define LE (L*E)   // 32768

typedef _Float16 f16;
typedef _Float16 f16x8 __attribute__((ext_vector_type(8)));
typedef float f32x4 __attribute__((ext_vector_type(4)));
typedef const __attribute__((address_space(1))) uint32_t gu32;
typedef __attribute__((address_space(3))) uint32_t lu32;

// ---------------------------------------------------------------------------
// Persistent state in module device globals. Everything rewritten every call.
// X/H images in FRAGMENT ORDER (r17): 64x64 image = 8 frags of 1 KB;
// frag = 16 rows x 32 k; addr = img + frag*1024 + lane*16.
// W' images: XOR layout, rows GATE-PLANAR per 64-col block (r18).
// r19: each wave keeps kt0..5 of B permanently in 192 VGPRs (B constant
// across steps; occupancy is 1 wave/SIMD so VGPRs<=~450 are free).
// ---------------------------------------------------------------------------
__device__ __align__(16) f16 g_Xs[128*16*4*4096];   // X images [t:128 pad][mt16][kt:4]
__device__ __align__(16) f16 g_Hh[128*16*8*4096];   // h(t) images, t=0..127 (134 MB)
__device__ __align__(16) f16 g_Ws[16*12*8192];      // gates W' [itile:16][kt:12] 128x64
__device__ __align__(16) f16 g_W1s[8*8192];         // W1' [kt:8] 128x64 (XOR layout)
__device__ __align__(16) f16 g_W2s[2*8192];         // W2' [kt:2]
__device__ __align__(16) f16 g_W3s[4*8192];         // W3' [nh:2][kt:2]
__device__ __align__(16) float g_bsum[2048];        // b_ih+b_hh, NATURAL order g*512+j

// r15-validated sync: groups = PHYSICAL XCDs, relaxed flags, no wbl2/inv.
struct __align__(128) Flag { unsigned int v; unsigned int pad[31]; };
__device__ Flag g_flags[8][32];
__device__ unsigned int g_slot[8];

__device__ __forceinline__ float fsigm(float x) {
    return __builtin_amdgcn_rcpf(1.0f + __expf(-x));
}
__device__ __forceinline__ float ftanh(float x) {
    return 2.0f * __builtin_amdgcn_rcpf(1.0f + __expf(-2.0f * x)) - 1.0f;
}

// ---------------------------------------------------------------------------
// conv_w: gates W' images, GATE-PLANAR rows (r18) + bias sums natural order
// ---------------------------------------------------------------------------
__global__ __launch_bounds__(256) void conv_w(
    const float* __restrict__ W_ih, const float* __restrict__ W_hh,
    const float* __restrict__ b_ih, const float* __restrict__ b_hh)
{
    int gid = blockIdx.x*256 + threadIdx.x;   // 196608
    int kb  = gid & 7;
    int r1  = gid >> 3;
    int row = r1 & 127;
    int r2  = r1 >> 7;
    int kt  = r2 % 12;
    int nt  = r2 / 12;
    int ntblock = nt*2 + (row >> 6);
    int c = row & 63;
    int wrow = (c >> 4)*512 + ntblock*16 + (c & 15);
    int k = kt*64 + kb*8;
    const float* src = (k < 256) ? (W_ih + wrow*256 + k)
                                 : (W_hh + wrow*512 + (k - 256));
    f16x8 v;
    #pragma unroll
    for (int e = 0; e < 8; ++e) v[e] = (f16)src[e];
    char* dst = (char*)g_Ws + (size_t)(nt*12 + kt)*16384
              + row*128 + ((kb*16) ^ ((row & 7) << 4));
    *(f16x8*)dst = v;
    if (gid < 2048) g_bsum[gid] = b_ih[gid] + b_hh[gid];
}

// ---------------------------------------------------------------------------
// conv_mlp: W1/W2/W3 fp16 tile images (XOR layout, unchanged)
// ---------------------------------------------------------------------------
__global__ __launch_bounds__(256) void conv_mlp(
    const float* __restrict__ W1, const float* __restrict__ W2,
    const float* __restrict__ W3)
{
    int gid = blockIdx.x*256 + threadIdx.x;   // 14336
    if (gid < 8192) {                         // W1 (128,512) -> 8 tiles
        int s = gid;
        int kb = s & 7, row = (s >> 3) & 127, kt = s >> 10;
        const float* src = W1 + row*512 + kt*64 + kb*8;
        f16x8 v;
        #pragma unroll
        for (int e = 0; e < 8; ++e) v[e] = (f16)src[e];
        char* dst = (char*)g_W1s + (size_t)kt*16384
                  + row*128 + ((kb*16) ^ ((row & 7) << 4));
        *(f16x8*)dst = v;
    } else if (gid < 10240) {                 // W2 (128,128) -> 2 tiles
        int s = gid - 8192;
        int kb = s & 7, row = (s >> 3) & 127, kt = s >> 10;
        const float* src = W2 + row*128 + kt*64 + kb*8;
        f16x8 v;
        #pragma unroll
        for (int e = 0; e < 8; ++e) v[e] = (f16)src[e];
        char* dst = (char*)g_W2s + (size_t)kt*16384
                  + row*128 + ((kb*16) ^ ((row & 7) << 4));
        *(f16x8*)dst = v;
    } else if (gid < 14336) {                 // W3 (256,128) -> [nh:2][kt:2]
        int s = gid - 10240;
        int kb = s & 7, r256 = (s >> 3) & 255, kt = s >> 11;
        int nh = r256 >> 7, row = r256 & 127;
        const float* src = W3 + r256*128 + kt*64 + kb*8;
        f16x8 v;
        #pragma unroll
        for (int e = 0; e < 8; ++e) v[e] = (f16)src[e];
        char* dst = (char*)g_W3s + (size_t)(nh*2 + kt)*16384
                  + row*128 + ((kb*16) ^ ((row & 7) << 4));
        *(f16x8*)dst = v;
    }
}

// ---------------------------------------------------------------------------
// conv_x: X fp16 images in FRAGMENT ORDER (unchanged from r17)
// ---------------------------------------------------------------------------
__global__ __launch_bounds__(256) void conv_x(const float* __restrict__ padded)
{
    int gid = blockIdx.x*256 + threadIdx.x;   // 127*1024*32 = 4161536 exact
    int kq = gid & 31;
    int b  = (gid >> 5) & 1023;
    int t  = gid >> 15;
    const float* src = padded + (size_t)b*LE + t*E + kq*8;
    float4 v0 = *(const float4*)src;
    float4 v1 = *(const float4*)(src + 4);
    f16x8 v;
    v[0]=(f16)v0.x; v[1]=(f16)v0.y; v[2]=(f16)v0.z; v[3]=(f16)v0.w;
    v[4]=(f16)v1.x; v[5]=(f16)v1.y; v[6]=(f16)v1.z; v[7]=(f16)v1.w;
    int ktimg = kq >> 3;
    int kin0  = (kq & 7) * 8;
    int kgrp  = kin0 >> 5;
    int chunk = (kin0 & 31) >> 3;
    int row = b & 63, mt16 = b >> 6;
    int rowgrp = row >> 4;
    int lane = (row & 15) | (chunk << 4);
    char* dst = (char*)g_Xs + (size_t)((t*16 + mt16)*4 + ktimg)*8192
              + (rowgrp*2 + kgrp)*1024 + lane*16;
    *(f16x8*)dst = v;
}

// ---------------------------------------------------------------------------
// init: g_Hh[0] <- hidden (fragment order), out row 0 <- one-hot, flags reset
// ---------------------------------------------------------------------------
__global__ __launch_bounds__(256) void init_kernel(
    const float* __restrict__ hidden, float* __restrict__ out)
{
    int i = blockIdx.x * 256 + threadIdx.x;
    if (i < 256) g_flags[i >> 5][i & 31].v = 0u;
    if (i < 8) g_slot[i] = 0u;
    if (i < B*H) {
        float hv = hidden[i];
        int b = i >> 9, j = i & 511;
        int mt = b >> 6, row = b & 63, ktimg = j >> 6, kin = j & 63;
        int rowgrp = row >> 4, kgrp = kin >> 5;
        int lane = (row & 15) | (((kin & 31) >> 3) << 4);
        int elem = kin & 7;
        char* dst = (char*)g_Hh + (size_t)(mt*8 + ktimg)*8192
                  + (rowgrp*2 + kgrp)*1024 + lane*16 + elem*2;
        *(f16*)dst = (f16)hv;
    }
    if (i < B*E) {
        int b = i >> 8, e = i & 255;
        out[b*LE + e] = (e == 0) ? 1.0f : 0.0f;
    }
}

// ---------------------------------------------------------------------------
// step_all: r18 structure + r19 B-in-registers for kt0..5.
// 8 groups (= physical XCDs) x 32 blocks, 256 threads. B kt0..5 in VGPRs
// (loaded once), kt6..11 from persistent LDS; A frags coalesced global->reg;
// zero s_barriers in the kt loop; shuffle-free gate-planar epilogue.
// ---------------------------------------------------------------------------
__global__ __launch_bounds__(256, 1) void step_all()
{
    __shared__ __align__(16) char lds[102400];   // 96K B + 4 x 1K wave Hs
    char* Bb = lds;

    const int tid  = threadIdx.x;
    const int lane = tid & 63;
    const int wv   = tid >> 6;          // 0..3
    const int l15  = lane & 15;
    const int quad = lane >> 4;
    const int klo  = quad << 4;
    f16* HsW = (f16*)(lds + 98304 + wv*1024);    // wave-private [32][16]

    // runtime grouping: grp = physical XCD, nt = slot within XCD.
    if (tid == 0) {
        uint32_t xcc;
        asm volatile("s_getreg_b32 %0, hwreg(HW_REG_XCC_ID)" : "=s"(xcc));
        xcc &= 7u;
        unsigned int slot = atomicAdd(&g_slot[xcc], 1u);
        ((int*)lds)[0] = (int)xcc;
        ((int*)lds)[1] = (int)(slot & 31u);
    }
    __syncthreads();
    const int grp = ((volatile int*)lds)[0];
    const int nt  = ((volatile int*)lds)[1];
    __syncthreads();   // reads done before B staging overwrites lds[0..7]

    // ---- persistent B load (once): rows (nt&1)*64..+64 of itile nt>>1 ----
    {
        const char* src = (const char*)g_Ws + (size_t)(nt >> 1)*12*16384
                        + (size_t)(nt & 1)*64*128;
        #pragma unroll
        for (int it = 0; it < 24; ++it) {
            int c = wv*24 + it;             // 0..95 chunks of 1KB
            int kt = c >> 3, cc = c & 7;
            __builtin_amdgcn_global_load_lds(
                (gu32*)(src + (size_t)kt*16384 + cc*1024 + lane*16),
                (lu32*)(Bb + c*1024 + lane*16), 16, 0, 0);
        }
    }
    // per-lane bias: gate g at col j = nt*16 + l15
    float bsv[4];
    #pragma unroll
    for (int g = 0; g < 4; ++g) bsv[g] = g_bsum[g*512 + nt*16 + l15];

    float creg[2][4];
    #pragma unroll
    for (int m = 0; m < 2; ++m)
        #pragma unroll
        for (int i = 0; i < 4; ++i) creg[m][i] = 0.0f;

    asm volatile("s_waitcnt vmcnt(0)" ::: "memory");
    __syncthreads();   // B resident for all waves

    // ---- r19: kt0..5 of B -> 192 VGPRs (constant across all steps) ----
    f16x8 bw[6][2][4];
    #pragma unroll
    for (int kt = 0; kt < 6; ++kt)
        #pragma unroll
        for (int kkl = 0; kkl < 2; ++kkl) {
            const int kb = kkl*64 + klo;
            #pragma unroll
            for (int n = 0; n < 4; ++n) {
                int r = n*16 + l15;
                bw[kt][kkl][n] = *(const f16x8*)(Bb + kt*8192 + r*128
                                                 + (kb ^ ((r & 7) << 4)));
            }
        }

    const int sub = wv >> 1;            // which 64-row image
    const int rg2 = (wv & 1) * 2;       // rowgrp base within image

    f16x8 az[3][4];
    auto loada = [&](int t_, int kt_, int s_) {
        const char* img = (kt_ < 4)
            ? (const char*)g_Xs + (size_t)((t_*16 + grp*2 + sub)*4 + kt_)*8192
            : (const char*)g_Hh + (size_t)((t_*16 + grp*2 + sub)*8 + (kt_-4))*8192;
        const char* fb = img + (size_t)(rg2*2)*1024 + lane*16;
        az[s_][0] = *(const f16x8*)(fb);
        az[s_][1] = *(const f16x8*)(fb + 1024);
        az[s_][2] = *(const f16x8*)(fb + 2048);
        az[s_][3] = *(const f16x8*)(fb + 3072);
    };

    auto wave_wait = [&](unsigned int target) {
        for (;;) {
            unsigned int v = __hip_atomic_load(&g_flags[grp][lane & 31].v,
                               __ATOMIC_RELAXED, __HIP_MEMORY_SCOPE_AGENT);
            if (__all(v >= target)) break;
            __builtin_amdgcn_s_sleep(1);
        }
        asm volatile("" ::: "memory");
    };

    // prologue: X(0) kt0..2
    loada(0, 0, 0); loada(0, 1, 1); loada(0, 2, 2);

    #pragma unroll 1
    for (int t = 0; t < 127; ++t) {
        f32x4 acc[2][4];
        #pragma unroll
        for (int m = 0; m < 2; ++m)
            #pragma unroll
            for (int n = 0; n < 4; ++n) acc[m][n] = (f32x4){0.f,0.f,0.f,0.f};

        #pragma unroll
        for (int kt = 0; kt < 12; ++kt) {
            const int s = kt % 3;
            #pragma unroll
            for (int kkl = 0; kkl < 2; ++kkl) {
                f16x8 b[4];
                if (kt < 6) {
                    #pragma unroll
                    for (int n = 0; n < 4; ++n) b[n] = bw[kt][kkl][n];
                } else {
                    const char* Br = Bb + kt*8192;
                    const int kb = kkl*64 + klo;
                    #pragma unroll
                    for (int n = 0; n < 4; ++n) {
                        int r = n*16 + l15;
                        b[n] = *(const f16x8*)(Br + r*128 + (kb ^ ((r & 7) << 4)));
                    }
                }
                #pragma unroll
                for (int n = 0; n < 4; ++n) {
                    acc[0][n] = __builtin_amdgcn_mfma_f32_16x16x32_f16(
                        az[s][0 + kkl], b[n], acc[0][n], 0, 0, 0);
                    acc[1][n] = __builtin_amdgcn_mfma_f32_16x16x32_f16(
                        az[s][2 + kkl], b[n], acc[1][n], 0, 0, 0);
                }
            }
            if (kt == 1) wave_wait((unsigned)t);   // h(t) visible before kt4 issue
            if (kt < 9) loada(t, kt + 3, s);
            else        loada(t + 1, kt - 9, s);   // X(t+1); g_Xs padded
        }

        // ---- shuffle-free epilogue: all 4 gates in-lane per cell ----
        #pragma unroll
        for (int m = 0; m < 2; ++m)
            #pragma unroll
            for (int i = 0; i < 4; ++i) {
                float iv = fsigm(acc[m][0][i] + bsv[0]);
                float fv = fsigm(acc[m][1][i] + bsv[1]);
                float gg = ftanh(acc[m][2][i] + bsv[2]);
                float ov = fsigm(acc[m][3][i] + bsv[3]);
                float cv = fv * creg[m][i] + iv * gg;
                creg[m][i] = cv;
                float hv = ov * ftanh(cv);
                int rowl = m*16 + quad*4 + i;       // 0..31 wave-local
                HsW[rowl*16 + l15] = (f16)hv;       // col = l15
            }
        asm volatile("s_waitcnt lgkmcnt(0)" ::: "memory");  // wave's Hs done
        // wave-private coalesced h store in FRAGMENT ORDER (unchanged r17)
        {
            int rg = lane >> 5, lo = lane & 31;
            int ktimg = nt >> 2;
            int kgrp  = (nt & 3) >> 1;
            int c0    = (nt & 1) * 2;
            char* img = (char*)g_Hh
                + (size_t)(((t + 1)*16 + grp*2 + sub)*8 + ktimg)*8192;
            int frag = (rg2 + rg)*2 + kgrp;
            f16x8 hv8 = *(const f16x8*)(HsW + (rg*16 + (lo & 15))*16 + (lo >> 4)*8);
            *(f16x8*)(img + frag*1024 + (size_t)(c0*16 + lo)*16) = hv8;
        }
        asm volatile("s_waitcnt vmcnt(0)" ::: "memory");  // h complete in L2
        __syncthreads();                                  // all waves done
        if (tid == 0)
            __hip_atomic_store(&g_flags[grp][nt].v, (unsigned)(t + 1),
                               __ATOMIC_RELAXED, __HIP_MEMORY_SCOPE_AGENT);
    }
}

// ---------------------------------------------------------------------------
// mlp_all: batched 3-layer MLP for ALL tokens (r17 structure, unchanged)
// ---------------------------------------------------------------------------
__global__ __launch_bounds__(256) void mlp_all(
    const float* __restrict__ b1, const float* __restrict__ b2,
    const float* __restrict__ b3, float* __restrict__ out)
{
    __shared__ char lds[65536];
    char* Wb = lds;            // 2 x 16384
    char* Ab = lds + 32768;    // 2 x 8192 (later Z2)
    char* Z1 = lds + 49152;    // 16384
    const int tid  = threadIdx.x;
    const int lane = tid & 63;
    const int w    = tid >> 6;
    const int bi   = blockIdx.x;
    const int tok  = 1 + (bi >> 4);
    const int mt   = bi & 15;
    const char* gH = (const char*)g_Hh + (size_t)(tok*16 + mt)*8*8192;
    float* outb = out + (size_t)(mt*64)*LE + (size_t)tok*E;

    float b1v[2], b2v[2], b3v[2][2];
    #pragma unroll
    for (int n = 0; n < 2; ++n) {
        int col = w*32 + n*16 + (lane & 15);
        b1v[n] = b1[col]; b2v[n] = b2[col];
        b3v[0][n] = b3[col]; b3v[1][n] = b3[128 + col];
    }
    const int kb0_0 = ((lane >> 4) << 4);

    f32x4 acc[4][2];
    #pragma unroll
    for (int m = 0; m < 4; ++m) { acc[m][0] = (f32x4){0,0,0,0}; acc[m][1] = (f32x4){0,0,0,0}; }

    #pragma unroll
    for (int it = 0; it < 2; ++it) {
        int c = w*2 + it;
        __builtin_amdgcn_global_load_lds((gu32*)(gH + c*1024 + lane*16),
                                         (lu32*)(Ab + c*1024 + lane*16), 16, 0, 0);
    }
    #pragma unroll
    for (int it = 0; it < 4; ++it) {
        int c = w*4 + it;
        __builtin_amdgcn_global_load_lds((gu32*)((const char*)g_W1s + c*1024 + lane*16),
                                         (lu32*)(Wb + c*1024 + lane*16), 16, 0, 0);
    }
    __syncthreads();

    for (int kt = 0; kt < 8; ++kt) {
        const int cur = kt & 1;
        if (kt < 7) {
            const char* gA = gH + (size_t)(kt+1)*8192;
            const char* gW = (const char*)g_W1s + (size_t)(kt+1)*16384;
            char* dA = Ab + (cur^1)*8192;
            char* dW = Wb + (cur^1)*16384;
            #pragma unroll
            for (int it = 0; it < 2; ++it) {
                int c = w*2 + it;
                __builtin_amdgcn_global_load_lds((gu32*)(gA + c*1024 + lane*16),
                                                 (lu32*)(dA + c*1024 + lane*16), 16, 0, 0);
            }
            #pragma unroll
            for (int it = 0; it < 4; ++it) {
                int c = w*4 + it;
                __builtin_amdgcn_global_load_lds((gu32*)(gW + c*1024 + lane*16),
                                                 (lu32*)(dW + c*1024 + lane*16), 16, 0, 0);
            }
        }
        const char* Ar = Ab + cur*8192;
        const char* Br = Wb + cur*16384;
        #pragma unroll
        for (int kk = 0; kk < 2; ++kk) {
            const int kb0 = kk*64 + kb0_0;
            f16x8 a[4], b[2];
            #pragma unroll
            for (int m = 0; m < 4; ++m)
                a[m] = *(const f16x8*)(Ar + (size_t)(m*2 + kk)*1024 + lane*16);
            #pragma unroll
            for (int n = 0; n < 2; ++n) {
                int br = w*32 + n*16 + (lane & 15);
                b[n] = *(const f16x8*)(Br + br*128 + (kb0 ^ ((br & 7) << 4)));
            }
            #pragma unroll
            for (int m = 0; m < 4; ++m)
                #pragma unroll
                for (int n = 0; n < 2; ++n)
                    acc[m][n] = __builtin_amdgcn_mfma_f32_16x16x32_f16(a[m], b[n], acc[m][n], 0, 0, 0);
        }
        __syncthreads();
    }

    #pragma unroll
    for (int m = 0; m < 4; ++m)
        #pragma unroll
        for (int n = 0; n < 2; ++n)
            #pragma unroll
            for (int i = 0; i < 4; ++i) {
                int row = m*16 + ((lane >> 4) << 2) + i;
                int col = w*32 + n*16 + (lane & 15);
                float v = fmaxf(acc[m][n][i] + b1v[n], 0.0f);
                *(f16*)(Z1 + (col >> 6)*8192 + row*128
                        + (((col & 63)*2) ^ ((row & 7) << 4))) = (f16)v;
            }
    __syncthreads();

    #pragma unroll
    for (int it = 0; it < 8; ++it) {
        int c = w*8 + it;
        __builtin_amdgcn_global_load_lds((gu32*)((const char*)g_W2s + c*1024 + lane*16),
                                         (lu32*)(Wb + c*1024 + lane*16), 16, 0, 0);
    }
    __syncthreads();
    #pragma unroll
    for (int m = 0; m < 4; ++m) { acc[m][0] = (f32x4){0,0,0,0}; acc[m][1] = (f32x4){0,0,0,0}; }
    #pragma unroll
    for (int kt = 0; kt < 2; ++kt)
        #pragma unroll
        for (int kk = 0; kk < 2; ++kk) {
            const int kb0 = kk*64 + kb0_0;
            f16x8 a[4], b[2];
            #pragma unroll
            for (int m = 0; m < 4; ++m) {
                int ar = m*16 + (lane & 15);
                a[m] = *(const f16x8*)(Z1 + kt*8192 + ar*128 + (kb0 ^ ((ar & 7) << 4)));
            }
            #pragma unroll
            for (int n = 0; n < 2; ++n) {
                int br = w*32 + n*16 + (lane & 15);
                b[n] = *(const f16x8*)(Wb + kt*16384 + br*128 + (kb0 ^ ((br & 7) << 4)));
            }
            #pragma unroll
            for (int m = 0; m < 4; ++m)
                #pragma unroll
                for (int n = 0; n < 2; ++n)
                    acc[m][n] = __builtin_amdgcn_mfma_f32_16x16x32_f16(a[m], b[n], acc[m][n], 0, 0, 0);
        }
    __syncthreads();

    #pragma unroll
    for (int m = 0; m < 4; ++m)
        #pragma unroll
        for (int n = 0; n < 2; ++n)
            #pragma unroll
            for (int i = 0; i < 4; ++i) {
                int row = m*16 + ((lane >> 4) << 2) + i;
                int col = w*32 + n*16 + (lane & 15);
                float v = fmaxf(acc[m][n][i] + b2v[n], 0.0f);
                *(f16*)(Ab + (col >> 6)*8192 + row*128
                        + (((col & 63)*2) ^ ((row & 7) << 4))) = (f16)v;
            }
    __syncthreads();

    #pragma unroll
    for (int nh = 0; nh < 2; ++nh) {
        #pragma unroll
        for (int it = 0; it < 8; ++it) {
            int c = w*8 + it;
            __builtin_amdgcn_global_load_lds(
                (gu32*)((const char*)g_W3s + (size_t)nh*32768 + c*1024 + lane*16),
                (lu32*)(Wb + c*1024 + lane*16), 16, 0, 0);
        }
        __syncthreads();
        #pragma unroll
        for (int m = 0; m < 4; ++m) { acc[m][0] = (f32x4){0,0,0,0}; acc[m][1] = (f32x4){0,0,0,0}; }
        #pragma unroll
        for (int kt = 0; kt < 2; ++kt)
            #pragma unroll
            for (int kk = 0; kk < 2; ++kk) {
                const int kb0 = kk*64 + kb0_0;
                f16x8 a[4], b[2];
                #pragma unroll
                for (int m = 0; m < 4; ++m) {
                    int ar = m*16 + (lane & 15);
                    a[m] = *(const f16x8*)(Ab + kt*8192 + ar*128 + (kb0 ^ ((ar & 7) << 4)));
                }
                #pragma unroll
                for (int n = 0; n < 2; ++n) {
                    int br = w*32 + n*16 + (lane & 15);
                    b[n] = *(const f16x8*)(Wb + kt*16384 + br*128 + (kb0 ^ ((br & 7) << 4)));
                }
                #pragma unroll
                for (int m = 0; m < 4; ++m)
                    #pragma unroll
                    for (int n = 0; n < 2; ++n)
                        acc[m][n] = __builtin_amdgcn_mfma_f32_16x16x32_f16(a[m], b[n], acc[m][n], 0, 0, 0);
            }
        #pragma unroll
        for (int m = 0; m < 4; ++m)
            #pragma unroll
            for (int n = 0; n < 2; ++n)
                #pragma unroll
                for (int i = 0; i < 4; ++i) {
                    int row = m*16 + ((lane >> 4) << 2) + i;
                    int col = nh*128 + w*32 + n*16 + (lane & 15);
                    outb[(size_t)row*LE + col] = acc[m][n][i] + b3v[nh][n];
                }
        __syncthreads();
    }
}

// ---------------------------------------------------------------------------
extern "C" void kernel_launch(void* const* d_in, const int* in_sizes, int n_in,
                              void* d_out, int out_size, void* d_ws, size_t ws_size,
                              hipStream_t stream) {
    (void)in_sizes; (void)n_in; (void)out_size; (void)d_ws; (void)ws_size;
    const float* hidden = (const float*)d_in[0];
    const float* padded = (const float*)d_in[1];
    const float* W_ih   = (const float*)d_in[2];
    const float* W_hh   = (const float*)d_in[3];
    const float* b_ih   = (const float*)d_in[4];
    const float* b_hh   = (const float*)d_in[5];
    const float* W1     = (const float*)d_in[6];
    const float* b1     = (const float*)d_in[7];
    const float* W2     = (const float*)d_in[8];
    const float* b2     = (const float*)d_in[9];
    const float* W3     = (const float*)d_in[10];
    const float* b3     = (const float*)d_in[11];
    float* out = (float*)d_out;

    conv_w<<<768, 256, 0, stream>>>(W_ih, W_hh, b_ih, b_hh);
    conv_mlp<<<56, 256, 0, stream>>>(W1, W2, W3);
    conv_x<<<16256, 256, 0, stream>>>(padded);
    init_kernel<<<2048, 256, 0, stream>>>(hidden, out);
    step_all<<<256, 256, 0, stream>>>();
    mlp_all<<<2032, 256, 0, stream>>>(b1, b2, b3, out);
}